// Round 2
// baseline (820.579 us; speedup 1.0000x reference)
//
#include <hip/hip_runtime.h>
#include <hip/hip_bf16.h>
#include <cstdint>

typedef __attribute__((ext_vector_type(8))) short bf16x8;
typedef __attribute__((ext_vector_type(4))) float f32x4;

constexpr int B = 8, S = 2048, D = 1024, H = 2048, N4 = 4096;
constexpr int M = B * S;                 // 16384 rows
constexpr int CHUNK = 128, NCH = S / CHUNK;
constexpr float EPS_LN = 1e-5f, EPS_SHIFT = 1e-5f;

// ---------- all scratch lives in a module-level device global ----------
// (round-1 timeout diagnosis: d_ws may be smaller than the ~309 MiB we need;
//  OOB writes on the workspace wedge the queue -> 600 s hang. A zero-init
//  __device__ global is allocated at module load, independent of ws_size,
//  and is graph-capture-safe.)
constexpr size_t SZ_XN    = (size_t)M * D * 2;       // LN(x) bf16
constexpr size_t SZ_HBUF  = (size_t)M * H * 2;       // h half (bf16), gated in place
constexpr size_t SZ_GATE  = (size_t)M * H * 4;       // gate fp32 -> LN -> cumsum (in place)
constexpr size_t SZ_SHIFT = (size_t)M * H * 2;       // shifted gate bf16
constexpr size_t SZ_WT1   = (size_t)N4 * D * 2;      // w_in^T  bf16
constexpr size_t SZ_WT2   = (size_t)H * H * 2;       // w_gate^T bf16
constexpr size_t SZ_WT3   = (size_t)D * H * 2;       // w_out^T bf16
constexpr size_t SZ_PART  = (size_t)B * NCH * H * 4; // cumsum partials

constexpr size_t OFF_XN    = 0;
constexpr size_t OFF_HBUF  = OFF_XN + SZ_XN;
constexpr size_t OFF_GATE  = OFF_HBUF + SZ_HBUF;
constexpr size_t OFF_SHIFT = OFF_GATE + SZ_GATE;
constexpr size_t OFF_WT1   = OFF_SHIFT + SZ_SHIFT;
constexpr size_t OFF_WT2   = OFF_WT1 + SZ_WT1;
constexpr size_t OFF_WT3   = OFF_WT2 + SZ_WT2;
constexpr size_t OFF_PART  = OFF_WT3 + SZ_WT3;
constexpr size_t TOTAL_WS  = OFF_PART + SZ_PART;     // ~309 MiB

__device__ __attribute__((aligned(1024))) unsigned char g_ws[TOTAL_WS];

__device__ __forceinline__ __hip_bfloat16* ws_xn()     { return (__hip_bfloat16*)(g_ws + OFF_XN); }
__device__ __forceinline__ __hip_bfloat16* ws_hbuf()   { return (__hip_bfloat16*)(g_ws + OFF_HBUF); }
__device__ __forceinline__ float*          ws_gate()   { return (float*)(g_ws + OFF_GATE); }
__device__ __forceinline__ __hip_bfloat16* ws_shift()  { return (__hip_bfloat16*)(g_ws + OFF_SHIFT); }
__device__ __forceinline__ __hip_bfloat16* ws_wt(int w){
    return (__hip_bfloat16*)(g_ws + (w == 0 ? OFF_WT1 : w == 1 ? OFF_WT2 : OFF_WT3));
}
__device__ __forceinline__ float*          ws_part()   { return (float*)(g_ws + OFF_PART); }

__device__ __forceinline__ void block_reduce2(float& s1, float& s2) {
    #pragma unroll
    for (int off = 32; off > 0; off >>= 1) {
        s1 += __shfl_xor(s1, off);
        s2 += __shfl_xor(s2, off);
    }
    __shared__ float buf[16];
    const int wid = threadIdx.x >> 6;
    const int nw = blockDim.x >> 6;
    if ((threadIdx.x & 63) == 0) { buf[wid] = s1; buf[8 + wid] = s2; }
    __syncthreads();
    if (threadIdx.x < 64) {
        float a = (threadIdx.x < nw) ? buf[threadIdx.x] : 0.f;
        float b = (threadIdx.x < nw) ? buf[8 + threadIdx.x] : 0.f;
        #pragma unroll
        for (int off = 4; off > 0; off >>= 1) { a += __shfl_xor(a, off); b += __shfl_xor(b, off); }
        if (threadIdx.x == 0) { buf[0] = a; buf[8] = b; }
    }
    __syncthreads();
    s1 = buf[0]; s2 = buf[8];
}

// ---- weight transpose + bf16 convert: in[R][C] fp32 -> ws[C][R] bf16 ----
__global__ __launch_bounds__(256) void transpose_bf16(
    const float* __restrict__ in, int which, int R, int C) {
    __hip_bfloat16* __restrict__ out = ws_wt(which);
    __shared__ float tile[32][33];
    const int c0 = blockIdx.x * 32, r0 = blockIdx.y * 32;
    const int tx = threadIdx.x, ty = threadIdx.y;   // block (32,8)
    #pragma unroll
    for (int j = 0; j < 4; ++j)
        tile[ty + j * 8][tx] = in[(size_t)(r0 + ty + j * 8) * C + c0 + tx];
    __syncthreads();
    #pragma unroll
    for (int j = 0; j < 4; ++j)
        out[(size_t)(c0 + ty + j * 8) * R + r0 + tx] = __float2bfloat16(tile[tx][ty + j * 8]);
}

// ---- LN over rows of 1024, fp32 -> bf16 (xn) ----
__global__ __launch_bounds__(256) void ln1024_kernel(
    const float* __restrict__ x, const float* __restrict__ w, const float* __restrict__ b) {
    __hip_bfloat16* __restrict__ out = ws_xn();
    const size_t row = blockIdx.x;
    const float4 v = reinterpret_cast<const float4*>(x + row * D)[threadIdx.x];
    float s = v.x + v.y + v.z + v.w;
    float q = v.x * v.x + v.y * v.y + v.z * v.z + v.w * v.w;
    block_reduce2(s, q);
    const float mu = s * (1.0f / D);
    const float var = q * (1.0f / D) - mu * mu;
    const float rs = rsqrtf(var + EPS_LN);
    const int c = threadIdx.x * 4;
    const float4 wv = reinterpret_cast<const float4*>(w)[threadIdx.x];
    const float4 bv = reinterpret_cast<const float4*>(b)[threadIdx.x];
    __hip_bfloat16* o = out + row * D + c;
    o[0] = __float2bfloat16((v.x - mu) * rs * wv.x + bv.x);
    o[1] = __float2bfloat16((v.y - mu) * rs * wv.y + bv.y);
    o[2] = __float2bfloat16((v.z - mu) * rs * wv.z + bv.z);
    o[3] = __float2bfloat16((v.w - mu) * rs * wv.w + bv.w);
}

// ---- LN over rows of 2048, fp32 in-place on gate ----
__global__ __launch_bounds__(512) void ln2048_inplace(
    const float* __restrict__ w, const float* __restrict__ b) {
    float* __restrict__ g = ws_gate();
    const size_t row = blockIdx.x;
    float4 v = reinterpret_cast<float4*>(g + row * H)[threadIdx.x];
    float s = v.x + v.y + v.z + v.w;
    float q = v.x * v.x + v.y * v.y + v.z * v.z + v.w * v.w;
    block_reduce2(s, q);
    const float mu = s * (1.0f / H);
    const float var = q * (1.0f / H) - mu * mu;
    const float rs = rsqrtf(var + EPS_LN);
    const float4 wv = reinterpret_cast<const float4*>(w)[threadIdx.x];
    const float4 bv = reinterpret_cast<const float4*>(b)[threadIdx.x];
    float4 o;
    o.x = (v.x - mu) * rs * wv.x + bv.x;
    o.y = (v.y - mu) * rs * wv.y + bv.y;
    o.z = (v.z - mu) * rs * wv.z + bv.z;
    o.w = (v.w - mu) * rs * wv.w + bv.w;
    reinterpret_cast<float4*>(g + row * H)[threadIdx.x] = o;
}

// ---- blocked cumsum along sequence, in-place on gate [B][S][H] ----
__global__ __launch_bounds__(256) void cumsum_p1() {
    const float* __restrict__ g = ws_gate();
    float* __restrict__ part = ws_part();
    const int idx = blockIdx.x * 256 + threadIdx.x;    // B*NCH*H
    const int c = idx & (H - 1);
    const int ch = (idx >> 11) & (NCH - 1);
    const int b = idx >> 15;
    const float* p = g + ((size_t)(b * S + ch * CHUNK)) * H + c;
    float s = 0.f;
    #pragma unroll 4
    for (int t = 0; t < CHUNK; ++t) s += p[(size_t)t * H];
    part[((size_t)b * NCH + ch) * H + c] = s;
}
__global__ __launch_bounds__(256) void cumsum_p2() {
    float* __restrict__ part = ws_part();
    const int idx = blockIdx.x * 256 + threadIdx.x;    // B*H
    const int c = idx & (H - 1);
    const int b = idx >> 11;
    float run = 0.f;
    for (int ch = 0; ch < NCH; ++ch) {
        const size_t o = ((size_t)b * NCH + ch) * H + c;
        const float v = part[o]; part[o] = run; run += v;
    }
}
__global__ __launch_bounds__(256) void cumsum_p3() {
    float* __restrict__ g = ws_gate();
    const float* __restrict__ part = ws_part();
    const int idx = blockIdx.x * 256 + threadIdx.x;
    const int c = idx & (H - 1);
    const int ch = (idx >> 11) & (NCH - 1);
    const int b = idx >> 15;
    float run = part[((size_t)b * NCH + ch) * H + c];
    float* p = g + ((size_t)(b * S + ch * CHUNK)) * H + c;
    for (int t = 0; t < CHUNK; ++t) { run += p[(size_t)t * H]; p[(size_t)t * H] = run; }
}

// ---- token shift from cumsum C [B][S][H] -> shifted bf16 [B][S][H] ----
__global__ __launch_bounds__(256) void shift_kernel() {
    const float* __restrict__ Cc = ws_gate();
    __hip_bfloat16* __restrict__ out = ws_shift();
    const size_t idx = (size_t)blockIdx.x * 256 + threadIdx.x;   // B*S*H
    const int c = (int)(idx & (H - 1));
    const int t = (int)((idx >> 11) & (S - 1));
    const int b = (int)(idx >> 22);
    const float* col = Cc + ((size_t)b * S) * H + c;
    const int blk = c >> 8;            // csize = 256
    float val;
    if (blk == 7) {                    // passthrough block: recover gate_n = C[t]-C[t-1]
        const float cur = col[(size_t)t * H];
        const float prev = t ? col[(size_t)(t - 1) * H] : 0.f;
        val = cur - prev;
    } else {
        const int a = 1 << blk;
        const float n1 = (t >= a)     ? col[(size_t)(t - a) * H]     : 0.f;
        const float n2 = (t >= 2 * a) ? col[(size_t)(t - 2 * a) * H] : 0.f;
        const float sd = (float)((t >= a ? t - a : 0) - (t >= 2 * a ? t - 2 * a : 0));
        val = (n1 - n2) / (sd + EPS_SHIFT);
    }
    out[idx] = __float2bfloat16(val);
}

// ---- bf16 MFMA GEMM: C = A[M][K] @ BT[N][K]^T, 128x128 tile, 4 waves ----
// EPI 0: A=xn, BT=wT1, K=D.  v=acc+b_in[col]; g=gelu(v); col<H -> hbuf, else gate fp32
// EPI 1: A=shifted, BT=wT2, K=H. v=acc+b_gate[col]; hbuf[row,col] *= v (bf16 in place)
// EPI 2: A=hbuf, BT=wT3, K=H. fout[row*D+col] = acc + b_out[col]
template<int EPI>
__global__ __launch_bounds__(256) void gemm_bt(
    const float* __restrict__ bias, float* __restrict__ fout)
{
    constexpr int K = (EPI == 0) ? D : H;
    const __hip_bfloat16* __restrict__ A =
        (EPI == 0) ? ws_xn() : (EPI == 1) ? ws_shift() : ws_hbuf();
    const __hip_bfloat16* __restrict__ BT = ws_wt(EPI);

    __shared__ __hip_bfloat16 lA[128 * 32];
    __shared__ __hip_bfloat16 lB[128 * 32];
    const int tid = threadIdx.x;
    const int lane = tid & 63;
    const int wv = tid >> 6;
    const int wr = wv >> 1, wc = wv & 1;
    const long bRow = (long)blockIdx.y * 128;
    const long bCol = (long)blockIdx.x * 128;

    f32x4 acc[4][4];
    #pragma unroll
    for (int m = 0; m < 4; ++m)
        #pragma unroll
        for (int n = 0; n < 4; ++n)
            acc[m][n] = {0.f, 0.f, 0.f, 0.f};

    for (int k0 = 0; k0 < K; k0 += 32) {
        __syncthreads();
        #pragma unroll
        for (int it = 0; it < 2; ++it) {
            const int chunk = it * 256 + tid;   // 512 chunks of 8 elems per tile
            const int row = chunk >> 2;
            const int kc = (chunk & 3) << 3;
            *(bf16x8*)(&lA[row * 32 + kc]) =
                *(const bf16x8*)(&A[(bRow + row) * (long)K + k0 + kc]);
            *(bf16x8*)(&lB[row * 32 + kc]) =
                *(const bf16x8*)(&BT[(bCol + row) * (long)K + k0 + kc]);
        }
        __syncthreads();
        const int lr = lane & 15;
        const int kk = (lane >> 4) << 3;
        bf16x8 af[4], bfr[4];
        #pragma unroll
        for (int m = 0; m < 4; ++m)
            af[m] = *(const bf16x8*)(&lA[(wr * 64 + m * 16 + lr) * 32 + kk]);
        #pragma unroll
        for (int n = 0; n < 4; ++n)
            bfr[n] = *(const bf16x8*)(&lB[(wc * 64 + n * 16 + lr) * 32 + kk]);
        #pragma unroll
        for (int m = 0; m < 4; ++m)
            #pragma unroll
            for (int n = 0; n < 4; ++n)
                acc[m][n] = __builtin_amdgcn_mfma_f32_16x16x32_bf16(af[m], bfr[n], acc[m][n], 0, 0, 0);
    }

    __hip_bfloat16* __restrict__ hbuf = ws_hbuf();
    float* __restrict__ gate = ws_gate();
    const int lr = lane & 15;
    const int lrow4 = (lane >> 4) << 2;   // C/D: col=lane&15, row=(lane>>4)*4+r  [m89/m91]
    #pragma unroll
    for (int m = 0; m < 4; ++m) {
        #pragma unroll
        for (int n = 0; n < 4; ++n) {
            const long col = bCol + wc * 64 + n * 16 + lr;
            const float bv = bias[col];
            #pragma unroll
            for (int r = 0; r < 4; ++r) {
                const long row = bRow + wr * 64 + m * 16 + lrow4 + r;
                float v = acc[m][n][r] + bv;
                if constexpr (EPI == 0) {
                    const float g = 0.5f * v * (1.0f + erff(v * 0.70710678118654752f));
                    if (col < H) hbuf[row * H + col] = __float2bfloat16(g);
                    else         gate[row * H + (col - H)] = g;
                } else if constexpr (EPI == 1) {
                    const long idx = row * H + col;
                    const float hv = __bfloat162float(hbuf[idx]);
                    hbuf[idx] = __float2bfloat16(hv * v);
                } else {
                    fout[row * D + col] = v;
                }
            }
        }
    }
}

extern "C" void kernel_launch(void* const* d_in, const int* in_sizes, int n_in,
                              void* d_out, int out_size, void* d_ws, size_t ws_size,
                              hipStream_t stream) {
    const float* x      = (const float*)d_in[0];
    const float* ln_w   = (const float*)d_in[1];
    const float* ln_b   = (const float*)d_in[2];
    const float* w_in   = (const float*)d_in[3];
    const float* b_in   = (const float*)d_in[4];
    const float* gln_w  = (const float*)d_in[5];
    const float* gln_b  = (const float*)d_in[6];
    const float* w_gate = (const float*)d_in[7];
    const float* b_gate = (const float*)d_in[8];
    const float* w_out  = (const float*)d_in[9];
    const float* b_out  = (const float*)d_in[10];
    float* out = (float*)d_out;
    (void)d_ws; (void)ws_size;   // scratch lives in g_ws (module global)

    const dim3 tb(32, 8);
    transpose_bf16<<<dim3(N4 / 32, D / 32), tb, 0, stream>>>(w_in,   0, D, N4);
    transpose_bf16<<<dim3(H / 32,  H / 32), tb, 0, stream>>>(w_gate, 1, H, H);
    transpose_bf16<<<dim3(D / 32,  H / 32), tb, 0, stream>>>(w_out,  2, H, D);

    ln1024_kernel<<<M, 256, 0, stream>>>(x, ln_w, ln_b);

    gemm_bt<0><<<dim3(N4 / 128, M / 128), 256, 0, stream>>>(b_in, nullptr);

    ln2048_inplace<<<M, 512, 0, stream>>>(gln_w, gln_b);
    cumsum_p1<<<(B * NCH * H) / 256, 256, 0, stream>>>();
    cumsum_p2<<<(B * H) / 256, 256, 0, stream>>>();
    cumsum_p3<<<(B * NCH * H) / 256, 256, 0, stream>>>();
    shift_kernel<<<(int)(((size_t)B * S * H) / 256), 256, 0, stream>>>();

    gemm_bt<1><<<dim3(H / 128, M / 128), 256, 0, stream>>>(b_gate, nullptr);
    gemm_bt<2><<<dim3(D / 128, M / 128), 256, 0, stream>>>(b_out, out);
}

// Round 3
// 723.746 us; speedup vs baseline: 1.1338x; 1.1338x over previous
//
#include <hip/hip_runtime.h>
#include <hip/hip_bf16.h>
#include <cstdint>

typedef __attribute__((ext_vector_type(8))) short bf16x8;
typedef __attribute__((ext_vector_type(4))) float f32x4;

constexpr int B = 8, S = 2048, D = 1024, H = 2048, N4 = 4096;
constexpr int M = B * S;                 // 16384 rows
constexpr int CHUNK = 128, NCH = S / CHUNK;
constexpr float EPS_LN = 1e-5f, EPS_SHIFT = 1e-5f;

// ---------- all scratch lives in a module-level device global ----------
constexpr size_t SZ_XN    = (size_t)M * D * 2;       // LN(x) bf16
constexpr size_t SZ_HBUF  = (size_t)M * H * 2;       // h half (bf16), gated in place
constexpr size_t SZ_GATE  = (size_t)M * H * 4;       // gate fp32 -> LN -> cumsum (in place)
constexpr size_t SZ_SHIFT = (size_t)M * H * 2;       // shifted gate bf16
constexpr size_t SZ_WT1   = (size_t)N4 * D * 2;      // w_in^T  bf16
constexpr size_t SZ_WT2   = (size_t)H * H * 2;       // w_gate^T bf16
constexpr size_t SZ_WT3   = (size_t)D * H * 2;       // w_out^T bf16
constexpr size_t SZ_PART  = (size_t)B * NCH * H * 4; // cumsum partials

constexpr size_t OFF_XN    = 0;
constexpr size_t OFF_HBUF  = OFF_XN + SZ_XN;
constexpr size_t OFF_GATE  = OFF_HBUF + SZ_HBUF;
constexpr size_t OFF_SHIFT = OFF_GATE + SZ_GATE;
constexpr size_t OFF_WT1   = OFF_SHIFT + SZ_SHIFT;
constexpr size_t OFF_WT2   = OFF_WT1 + SZ_WT1;
constexpr size_t OFF_WT3   = OFF_WT2 + SZ_WT2;
constexpr size_t OFF_PART  = OFF_WT3 + SZ_WT3;
constexpr size_t TOTAL_WS  = OFF_PART + SZ_PART;     // ~309 MiB

__device__ __attribute__((aligned(1024))) unsigned char g_ws[TOTAL_WS];

__device__ __forceinline__ __hip_bfloat16* ws_xn()     { return (__hip_bfloat16*)(g_ws + OFF_XN); }
__device__ __forceinline__ __hip_bfloat16* ws_hbuf()   { return (__hip_bfloat16*)(g_ws + OFF_HBUF); }
__device__ __forceinline__ float*          ws_gate()   { return (float*)(g_ws + OFF_GATE); }
__device__ __forceinline__ __hip_bfloat16* ws_shift()  { return (__hip_bfloat16*)(g_ws + OFF_SHIFT); }
__device__ __forceinline__ __hip_bfloat16* ws_wt(int w){
    return (__hip_bfloat16*)(g_ws + (w == 0 ? OFF_WT1 : w == 1 ? OFF_WT2 : OFF_WT3));
}
__device__ __forceinline__ float*          ws_part()   { return (float*)(g_ws + OFF_PART); }

// async global->LDS DMA, 16 B per lane (dest must be wave-uniform base + lane*16)
__device__ __forceinline__ void gload_lds16(const __hip_bfloat16* gsrc, __hip_bfloat16* ldst) {
    __builtin_amdgcn_global_load_lds(
        (const __attribute__((address_space(1))) void*)gsrc,
        (__attribute__((address_space(3))) void*)ldst, 16, 0, 0);
}

__device__ __forceinline__ void block_reduce2(float& s1, float& s2) {
    #pragma unroll
    for (int off = 32; off > 0; off >>= 1) {
        s1 += __shfl_xor(s1, off);
        s2 += __shfl_xor(s2, off);
    }
    __shared__ float buf[16];
    const int wid = threadIdx.x >> 6;
    const int nw = blockDim.x >> 6;
    if ((threadIdx.x & 63) == 0) { buf[wid] = s1; buf[8 + wid] = s2; }
    __syncthreads();
    if (threadIdx.x < 64) {
        float a = (threadIdx.x < nw) ? buf[threadIdx.x] : 0.f;
        float b = (threadIdx.x < nw) ? buf[8 + threadIdx.x] : 0.f;
        #pragma unroll
        for (int off = 4; off > 0; off >>= 1) { a += __shfl_xor(a, off); b += __shfl_xor(b, off); }
        if (threadIdx.x == 0) { buf[0] = a; buf[8] = b; }
    }
    __syncthreads();
    s1 = buf[0]; s2 = buf[8];
}

// ---- weight transpose + bf16 convert: in[R][C] fp32 -> ws[C][R] bf16 ----
__global__ __launch_bounds__(256) void transpose_bf16(
    const float* __restrict__ in, int which, int R, int C) {
    __hip_bfloat16* __restrict__ out = ws_wt(which);
    __shared__ float tile[32][33];
    const int c0 = blockIdx.x * 32, r0 = blockIdx.y * 32;
    const int tx = threadIdx.x, ty = threadIdx.y;   // block (32,8)
    #pragma unroll
    for (int j = 0; j < 4; ++j)
        tile[ty + j * 8][tx] = in[(size_t)(r0 + ty + j * 8) * C + c0 + tx];
    __syncthreads();
    #pragma unroll
    for (int j = 0; j < 4; ++j)
        out[(size_t)(c0 + ty + j * 8) * R + r0 + tx] = __float2bfloat16(tile[tx][ty + j * 8]);
}

// ---- LN over rows of 1024, fp32 -> bf16 (xn) ----
__global__ __launch_bounds__(256) void ln1024_kernel(
    const float* __restrict__ x, const float* __restrict__ w, const float* __restrict__ b) {
    __hip_bfloat16* __restrict__ out = ws_xn();
    const size_t row = blockIdx.x;
    const float4 v = reinterpret_cast<const float4*>(x + row * D)[threadIdx.x];
    float s = v.x + v.y + v.z + v.w;
    float q = v.x * v.x + v.y * v.y + v.z * v.z + v.w * v.w;
    block_reduce2(s, q);
    const float mu = s * (1.0f / D);
    const float var = q * (1.0f / D) - mu * mu;
    const float rs = rsqrtf(var + EPS_LN);
    const int c = threadIdx.x * 4;
    const float4 wv = reinterpret_cast<const float4*>(w)[threadIdx.x];
    const float4 bv = reinterpret_cast<const float4*>(b)[threadIdx.x];
    __hip_bfloat16* o = out + row * D + c;
    o[0] = __float2bfloat16((v.x - mu) * rs * wv.x + bv.x);
    o[1] = __float2bfloat16((v.y - mu) * rs * wv.y + bv.y);
    o[2] = __float2bfloat16((v.z - mu) * rs * wv.z + bv.z);
    o[3] = __float2bfloat16((v.w - mu) * rs * wv.w + bv.w);
}

// ---- LN over rows of 2048, fp32 in-place on gate ----
__global__ __launch_bounds__(512) void ln2048_inplace(
    const float* __restrict__ w, const float* __restrict__ b) {
    float* __restrict__ g = ws_gate();
    const size_t row = blockIdx.x;
    float4 v = reinterpret_cast<float4*>(g + row * H)[threadIdx.x];
    float s = v.x + v.y + v.z + v.w;
    float q = v.x * v.x + v.y * v.y + v.z * v.z + v.w * v.w;
    block_reduce2(s, q);
    const float mu = s * (1.0f / H);
    const float var = q * (1.0f / H) - mu * mu;
    const float rs = rsqrtf(var + EPS_LN);
    const float4 wv = reinterpret_cast<const float4*>(w)[threadIdx.x];
    const float4 bv = reinterpret_cast<const float4*>(b)[threadIdx.x];
    float4 o;
    o.x = (v.x - mu) * rs * wv.x + bv.x;
    o.y = (v.y - mu) * rs * wv.y + bv.y;
    o.z = (v.z - mu) * rs * wv.z + bv.z;
    o.w = (v.w - mu) * rs * wv.w + bv.w;
    reinterpret_cast<float4*>(g + row * H)[threadIdx.x] = o;
}

// ---- blocked cumsum along sequence, in-place on gate [B][S][H] ----
__global__ __launch_bounds__(256) void cumsum_p1() {
    const float* __restrict__ g = ws_gate();
    float* __restrict__ part = ws_part();
    const int idx = blockIdx.x * 256 + threadIdx.x;    // B*NCH*H
    const int c = idx & (H - 1);
    const int ch = (idx >> 11) & (NCH - 1);
    const int b = idx >> 15;
    const float* p = g + ((size_t)(b * S + ch * CHUNK)) * H + c;
    float s = 0.f;
    #pragma unroll 4
    for (int t = 0; t < CHUNK; ++t) s += p[(size_t)t * H];
    part[((size_t)b * NCH + ch) * H + c] = s;
}
__global__ __launch_bounds__(256) void cumsum_p2() {
    float* __restrict__ part = ws_part();
    const int idx = blockIdx.x * 256 + threadIdx.x;    // B*H
    const int c = idx & (H - 1);
    const int b = idx >> 11;
    float run = 0.f;
    for (int ch = 0; ch < NCH; ++ch) {
        const size_t o = ((size_t)b * NCH + ch) * H + c;
        const float v = part[o]; part[o] = run; run += v;
    }
}
__global__ __launch_bounds__(256) void cumsum_p3() {
    float* __restrict__ g = ws_gate();
    const float* __restrict__ part = ws_part();
    const int idx = blockIdx.x * 256 + threadIdx.x;
    const int c = idx & (H - 1);
    const int ch = (idx >> 11) & (NCH - 1);
    const int b = idx >> 15;
    float run = part[((size_t)b * NCH + ch) * H + c];
    float* p = g + ((size_t)(b * S + ch * CHUNK)) * H + c;
    for (int t = 0; t < CHUNK; ++t) { run += p[(size_t)t * H]; p[(size_t)t * H] = run; }
}

// ---- token shift from cumsum C [B][S][H] -> shifted bf16 [B][S][H] ----
__global__ __launch_bounds__(256) void shift_kernel() {
    const float* __restrict__ Cc = ws_gate();
    __hip_bfloat16* __restrict__ out = ws_shift();
    const size_t idx = (size_t)blockIdx.x * 256 + threadIdx.x;   // B*S*H
    const int c = (int)(idx & (H - 1));
    const int t = (int)((idx >> 11) & (S - 1));
    const int b = (int)(idx >> 22);
    const float* col = Cc + ((size_t)b * S) * H + c;
    const int blk = c >> 8;            // csize = 256
    float val;
    if (blk == 7) {                    // passthrough block: recover gate_n = C[t]-C[t-1]
        const float cur = col[(size_t)t * H];
        const float prev = t ? col[(size_t)(t - 1) * H] : 0.f;
        val = cur - prev;
    } else {
        const int a = 1 << blk;
        const float n1 = (t >= a)     ? col[(size_t)(t - a) * H]     : 0.f;
        const float n2 = (t >= 2 * a) ? col[(size_t)(t - 2 * a) * H] : 0.f;
        const float sd = (float)((t >= a ? t - a : 0) - (t >= 2 * a ? t - 2 * a : 0));
        val = (n1 - n2) / (sd + EPS_SHIFT);
    }
    out[idx] = __float2bfloat16(val);
}

// ---- bf16 MFMA GEMM: C = A[M][K] @ BT[N][K]^T, 128x128 tile, 4 waves ----
// Staging via global_load_lds width-16 (m97/m151: 646->874 TF vs reg-staging).
// LDS layout is linear in lane order: chunk t -> byte offset t*16 (wave-uniform
// base + lane*16, required by the DMA — m104). __syncthreads() drains vmcnt(0).
// EPI 0: A=xn, BT=wT1, K=D.  v=acc+b_in[col]; g=gelu(v); col<H -> hbuf, else gate fp32
// EPI 1: A=shifted, BT=wT2, K=H. v=acc+b_gate[col]; hbuf[row,col] *= v (bf16 in place)
// EPI 2: A=hbuf, BT=wT3, K=H. fout[row*D+col] = acc + b_out[col]
template<int EPI>
__global__ __launch_bounds__(256) void gemm_bt(
    const float* __restrict__ bias, float* __restrict__ fout)
{
    constexpr int K = (EPI == 0) ? D : H;
    const __hip_bfloat16* __restrict__ A =
        (EPI == 0) ? ws_xn() : (EPI == 1) ? ws_shift() : ws_hbuf();
    const __hip_bfloat16* __restrict__ BT = ws_wt(EPI);

    __shared__ __hip_bfloat16 lA[128 * 32];
    __shared__ __hip_bfloat16 lB[128 * 32];
    const int tid = threadIdx.x;
    const int lane = tid & 63;
    const int wv = tid >> 6;
    const int wr = wv >> 1, wc = wv & 1;
    const long bRow = (long)blockIdx.y * 128;
    const long bCol = (long)blockIdx.x * 128;

    f32x4 acc[4][4];
    #pragma unroll
    for (int m = 0; m < 4; ++m)
        #pragma unroll
        for (int n = 0; n < 4; ++n)
            acc[m][n] = {0.f, 0.f, 0.f, 0.f};

    // staging geometry: chunk c in [0,512): row = c>>2, kcol = (c&3)*8 elems.
    // issue 0: chunk=tid, issue 1: chunk=256+tid; LDS elem offset = chunk*8.
    const int srow = tid >> 2;
    const int skc = (tid & 3) << 3;

    for (int k0 = 0; k0 < K; k0 += 32) {
        __syncthreads();                           // previous tile fully consumed
        gload_lds16(&A [(bRow + srow)      * (long)K + k0 + skc], &lA[tid * 8]);
        gload_lds16(&BT[(bCol + srow)      * (long)K + k0 + skc], &lB[tid * 8]);
        gload_lds16(&A [(bRow + 64 + srow) * (long)K + k0 + skc], &lA[2048 + tid * 8]);
        gload_lds16(&BT[(bCol + 64 + srow) * (long)K + k0 + skc], &lB[2048 + tid * 8]);
        __syncthreads();                           // vmcnt(0) drained before barrier

        const int lr = lane & 15;
        const int kk = (lane >> 4) << 3;
        bf16x8 af[4], bfr[4];
        #pragma unroll
        for (int m = 0; m < 4; ++m)
            af[m] = *(const bf16x8*)(&lA[(wr * 64 + m * 16 + lr) * 32 + kk]);
        #pragma unroll
        for (int n = 0; n < 4; ++n)
            bfr[n] = *(const bf16x8*)(&lB[(wc * 64 + n * 16 + lr) * 32 + kk]);
        #pragma unroll
        for (int m = 0; m < 4; ++m)
            #pragma unroll
            for (int n = 0; n < 4; ++n)
                acc[m][n] = __builtin_amdgcn_mfma_f32_16x16x32_bf16(af[m], bfr[n], acc[m][n], 0, 0, 0);
    }

    __hip_bfloat16* __restrict__ hbuf = ws_hbuf();
    float* __restrict__ gate = ws_gate();
    const int lr = lane & 15;
    const int lrow4 = (lane >> 4) << 2;   // C/D: col=lane&15, row=(lane>>4)*4+r  [m89/m91]
    #pragma unroll
    for (int m = 0; m < 4; ++m) {
        #pragma unroll
        for (int n = 0; n < 4; ++n) {
            const long col = bCol + wc * 64 + n * 16 + lr;
            const float bv = bias[col];
            #pragma unroll
            for (int r = 0; r < 4; ++r) {
                const long row = bRow + wr * 64 + m * 16 + lrow4 + r;
                float v = acc[m][n][r] + bv;
                if constexpr (EPI == 0) {
                    const float g = 0.5f * v * (1.0f + erff(v * 0.70710678118654752f));
                    if (col < H) hbuf[row * H + col] = __float2bfloat16(g);
                    else         gate[row * H + (col - H)] = g;
                } else if constexpr (EPI == 1) {
                    const long idx = row * H + col;
                    const float hv = __bfloat162float(hbuf[idx]);
                    hbuf[idx] = __float2bfloat16(hv * v);
                } else {
                    fout[row * D + col] = v;
                }
            }
        }
    }
}

extern "C" void kernel_launch(void* const* d_in, const int* in_sizes, int n_in,
                              void* d_out, int out_size, void* d_ws, size_t ws_size,
                              hipStream_t stream) {
    const float* x      = (const float*)d_in[0];
    const float* ln_w   = (const float*)d_in[1];
    const float* ln_b   = (const float*)d_in[2];
    const float* w_in   = (const float*)d_in[3];
    const float* b_in   = (const float*)d_in[4];
    const float* gln_w  = (const float*)d_in[5];
    const float* gln_b  = (const float*)d_in[6];
    const float* w_gate = (const float*)d_in[7];
    const float* b_gate = (const float*)d_in[8];
    const float* w_out  = (const float*)d_in[9];
    const float* b_out  = (const float*)d_in[10];
    float* out = (float*)d_out;
    (void)d_ws; (void)ws_size;   // scratch lives in g_ws (module global)

    const dim3 tb(32, 8);
    transpose_bf16<<<dim3(N4 / 32, D / 32), tb, 0, stream>>>(w_in,   0, D, N4);
    transpose_bf16<<<dim3(H / 32,  H / 32), tb, 0, stream>>>(w_gate, 1, H, H);
    transpose_bf16<<<dim3(D / 32,  H / 32), tb, 0, stream>>>(w_out,  2, H, D);

    ln1024_kernel<<<M, 256, 0, stream>>>(x, ln_w, ln_b);

    gemm_bt<0><<<dim3(N4 / 128, M / 128), 256, 0, stream>>>(b_in, nullptr);

    ln2048_inplace<<<M, 512, 0, stream>>>(gln_w, gln_b);
    cumsum_p1<<<(B * NCH * H) / 256, 256, 0, stream>>>();
    cumsum_p2<<<(B * H) / 256, 256, 0, stream>>>();
    cumsum_p3<<<(B * NCH * H) / 256, 256, 0, stream>>>();
    shift_kernel<<<(int)(((size_t)B * S * H) / 256), 256, 0, stream>>>();

    gemm_bt<1><<<dim3(H / 128, M / 128), 256, 0, stream>>>(b_gate, nullptr);
    gemm_bt<2><<<dim3(D / 128, M / 128), 256, 0, stream>>>(b_out, out);
}

// Round 4
// 672.144 us; speedup vs baseline: 1.2208x; 1.0768x over previous
//
#include <hip/hip_runtime.h>
#include <hip/hip_bf16.h>
#include <cstdint>

typedef __attribute__((ext_vector_type(8))) short bf16x8;
typedef __attribute__((ext_vector_type(4))) float f32x4;

constexpr int B = 8, S = 2048, D = 1024, H = 2048, N4 = 4096;
constexpr int M = B * S;                 // 16384 rows
constexpr int CHUNK = 128, NCH = S / CHUNK;
constexpr float EPS_LN = 1e-5f, EPS_SHIFT = 1e-5f;

// ---------- all scratch lives in a module-level device global ----------
constexpr size_t SZ_XN    = (size_t)M * D * 2;       // LN(x) bf16
constexpr size_t SZ_HBUF  = (size_t)M * H * 2;       // h half (bf16), gated in place
constexpr size_t SZ_GATE  = (size_t)M * H * 4;       // gate fp32 -> LN -> cumsum (in place)
constexpr size_t SZ_SHIFT = (size_t)M * H * 2;       // shifted gate bf16
constexpr size_t SZ_WT1   = (size_t)N4 * D * 2;      // w_in^T  bf16
constexpr size_t SZ_WT2   = (size_t)H * H * 2;       // w_gate^T bf16
constexpr size_t SZ_WT3   = (size_t)D * H * 2;       // w_out^T bf16
constexpr size_t SZ_PART  = (size_t)B * NCH * H * 4; // cumsum partials

constexpr size_t OFF_XN    = 0;
constexpr size_t OFF_HBUF  = OFF_XN + SZ_XN;
constexpr size_t OFF_GATE  = OFF_HBUF + SZ_HBUF;
constexpr size_t OFF_SHIFT = OFF_GATE + SZ_GATE;
constexpr size_t OFF_WT1   = OFF_SHIFT + SZ_SHIFT;
constexpr size_t OFF_WT2   = OFF_WT1 + SZ_WT1;
constexpr size_t OFF_WT3   = OFF_WT2 + SZ_WT2;
constexpr size_t OFF_PART  = OFF_WT3 + SZ_WT3;
constexpr size_t TOTAL_WS  = OFF_PART + SZ_PART;     // ~309 MiB

__device__ __attribute__((aligned(1024))) unsigned char g_ws[TOTAL_WS];

__device__ __forceinline__ __hip_bfloat16* ws_xn()     { return (__hip_bfloat16*)(g_ws + OFF_XN); }
__device__ __forceinline__ __hip_bfloat16* ws_hbuf()   { return (__hip_bfloat16*)(g_ws + OFF_HBUF); }
__device__ __forceinline__ float*          ws_gate()   { return (float*)(g_ws + OFF_GATE); }
__device__ __forceinline__ __hip_bfloat16* ws_shift()  { return (__hip_bfloat16*)(g_ws + OFF_SHIFT); }
__device__ __forceinline__ __hip_bfloat16* ws_wt(int w){
    return (__hip_bfloat16*)(g_ws + (w == 0 ? OFF_WT1 : w == 1 ? OFF_WT2 : OFF_WT3));
}
__device__ __forceinline__ float*          ws_part()   { return (float*)(g_ws + OFF_PART); }

// async global->LDS DMA, 16 B per lane (dest must be wave-uniform base + lane*16)
__device__ __forceinline__ void gload_lds16(const __hip_bfloat16* gsrc, __hip_bfloat16* ldst) {
    __builtin_amdgcn_global_load_lds(
        (const __attribute__((address_space(1))) void*)gsrc,
        (__attribute__((address_space(3))) void*)ldst, 16, 0, 0);
}

__device__ __forceinline__ void phase_barrier() {
    asm volatile("" ::: "memory");
    __builtin_amdgcn_s_barrier();
    asm volatile("" ::: "memory");
}

__device__ __forceinline__ void block_reduce2(float& s1, float& s2) {
    #pragma unroll
    for (int off = 32; off > 0; off >>= 1) {
        s1 += __shfl_xor(s1, off);
        s2 += __shfl_xor(s2, off);
    }
    __shared__ float buf[16];
    const int wid = threadIdx.x >> 6;
    const int nw = blockDim.x >> 6;
    if ((threadIdx.x & 63) == 0) { buf[wid] = s1; buf[8 + wid] = s2; }
    __syncthreads();
    if (threadIdx.x < 64) {
        float a = (threadIdx.x < nw) ? buf[threadIdx.x] : 0.f;
        float b = (threadIdx.x < nw) ? buf[8 + threadIdx.x] : 0.f;
        #pragma unroll
        for (int off = 4; off > 0; off >>= 1) { a += __shfl_xor(a, off); b += __shfl_xor(b, off); }
        if (threadIdx.x == 0) { buf[0] = a; buf[8] = b; }
    }
    __syncthreads();
    s1 = buf[0]; s2 = buf[8];
}

// ---- weight transpose + bf16 convert: in[R][C] fp32 -> ws[C][R] bf16 ----
__global__ __launch_bounds__(256) void transpose_bf16(
    const float* __restrict__ in, int which, int R, int C) {
    __hip_bfloat16* __restrict__ out = ws_wt(which);
    __shared__ float tile[32][33];
    const int c0 = blockIdx.x * 32, r0 = blockIdx.y * 32;
    const int tx = threadIdx.x, ty = threadIdx.y;   // block (32,8)
    #pragma unroll
    for (int j = 0; j < 4; ++j)
        tile[ty + j * 8][tx] = in[(size_t)(r0 + ty + j * 8) * C + c0 + tx];
    __syncthreads();
    #pragma unroll
    for (int j = 0; j < 4; ++j)
        out[(size_t)(c0 + ty + j * 8) * R + r0 + tx] = __float2bfloat16(tile[tx][ty + j * 8]);
}

// ---- LN over rows of 1024, fp32 -> bf16 (xn) ----
__global__ __launch_bounds__(256) void ln1024_kernel(
    const float* __restrict__ x, const float* __restrict__ w, const float* __restrict__ b) {
    __hip_bfloat16* __restrict__ out = ws_xn();
    const size_t row = blockIdx.x;
    const float4 v = reinterpret_cast<const float4*>(x + row * D)[threadIdx.x];
    float s = v.x + v.y + v.z + v.w;
    float q = v.x * v.x + v.y * v.y + v.z * v.z + v.w * v.w;
    block_reduce2(s, q);
    const float mu = s * (1.0f / D);
    const float var = q * (1.0f / D) - mu * mu;
    const float rs = rsqrtf(var + EPS_LN);
    const int c = threadIdx.x * 4;
    const float4 wv = reinterpret_cast<const float4*>(w)[threadIdx.x];
    const float4 bv = reinterpret_cast<const float4*>(b)[threadIdx.x];
    __hip_bfloat16* o = out + row * D + c;
    o[0] = __float2bfloat16((v.x - mu) * rs * wv.x + bv.x);
    o[1] = __float2bfloat16((v.y - mu) * rs * wv.y + bv.y);
    o[2] = __float2bfloat16((v.z - mu) * rs * wv.z + bv.z);
    o[3] = __float2bfloat16((v.w - mu) * rs * wv.w + bv.w);
}

// ---- LN over rows of 2048, fp32 in-place on gate ----
__global__ __launch_bounds__(512) void ln2048_inplace(
    const float* __restrict__ w, const float* __restrict__ b) {
    float* __restrict__ g = ws_gate();
    const size_t row = blockIdx.x;
    float4 v = reinterpret_cast<float4*>(g + row * H)[threadIdx.x];
    float s = v.x + v.y + v.z + v.w;
    float q = v.x * v.x + v.y * v.y + v.z * v.z + v.w * v.w;
    block_reduce2(s, q);
    const float mu = s * (1.0f / H);
    const float var = q * (1.0f / H) - mu * mu;
    const float rs = rsqrtf(var + EPS_LN);
    const float4 wv = reinterpret_cast<const float4*>(w)[threadIdx.x];
    const float4 bv = reinterpret_cast<const float4*>(b)[threadIdx.x];
    float4 o;
    o.x = (v.x - mu) * rs * wv.x + bv.x;
    o.y = (v.y - mu) * rs * wv.y + bv.y;
    o.z = (v.z - mu) * rs * wv.z + bv.z;
    o.w = (v.w - mu) * rs * wv.w + bv.w;
    reinterpret_cast<float4*>(g + row * H)[threadIdx.x] = o;
}

// ---- blocked cumsum along sequence, in-place on gate [B][S][H] ----
__global__ __launch_bounds__(256) void cumsum_p1() {
    const float* __restrict__ g = ws_gate();
    float* __restrict__ part = ws_part();
    const int idx = blockIdx.x * 256 + threadIdx.x;    // B*NCH*H
    const int c = idx & (H - 1);
    const int ch = (idx >> 11) & (NCH - 1);
    const int b = idx >> 15;
    const float* p = g + ((size_t)(b * S + ch * CHUNK)) * H + c;
    float s = 0.f;
    #pragma unroll 4
    for (int t = 0; t < CHUNK; ++t) s += p[(size_t)t * H];
    part[((size_t)b * NCH + ch) * H + c] = s;
}
__global__ __launch_bounds__(256) void cumsum_p2() {
    float* __restrict__ part = ws_part();
    const int idx = blockIdx.x * 256 + threadIdx.x;    // B*H
    const int c = idx & (H - 1);
    const int b = idx >> 11;
    float run = 0.f;
    for (int ch = 0; ch < NCH; ++ch) {
        const size_t o = ((size_t)b * NCH + ch) * H + c;
        const float v = part[o]; part[o] = run; run += v;
    }
}
__global__ __launch_bounds__(256) void cumsum_p3() {
    float* __restrict__ g = ws_gate();
    const float* __restrict__ part = ws_part();
    const int idx = blockIdx.x * 256 + threadIdx.x;
    const int c = idx & (H - 1);
    const int ch = (idx >> 11) & (NCH - 1);
    const int b = idx >> 15;
    float run = part[((size_t)b * NCH + ch) * H + c];
    float* p = g + ((size_t)(b * S + ch * CHUNK)) * H + c;
    for (int t = 0; t < CHUNK; ++t) { run += p[(size_t)t * H]; p[(size_t)t * H] = run; }
}

// ---- token shift from cumsum C [B][S][H] -> shifted bf16 [B][S][H] ----
__global__ __launch_bounds__(256) void shift_kernel() {
    const float* __restrict__ Cc = ws_gate();
    __hip_bfloat16* __restrict__ out = ws_shift();
    const size_t idx = (size_t)blockIdx.x * 256 + threadIdx.x;   // B*S*H
    const int c = (int)(idx & (H - 1));
    const int t = (int)((idx >> 11) & (S - 1));
    const int b = (int)(idx >> 22);
    const float* col = Cc + ((size_t)b * S) * H + c;
    const int blk = c >> 8;            // csize = 256
    float val;
    if (blk == 7) {                    // passthrough block: recover gate_n = C[t]-C[t-1]
        const float cur = col[(size_t)t * H];
        const float prev = t ? col[(size_t)(t - 1) * H] : 0.f;
        val = cur - prev;
    } else {
        const int a = 1 << blk;
        const float n1 = (t >= a)     ? col[(size_t)(t - a) * H]     : 0.f;
        const float n2 = (t >= 2 * a) ? col[(size_t)(t - 2 * a) * H] : 0.f;
        const float sd = (float)((t >= a ? t - a : 0) - (t >= 2 * a ? t - 2 * a : 0));
        val = (n1 - n2) / (sd + EPS_SHIFT);
    }
    out[idx] = __float2bfloat16(val);
}

// ============================================================================
// 256x256-tile 8-phase MFMA GEMM (T3+T4+T5 port, BK=32, 4 LDS buffers).
//   C = A[M][K] @ BT[N][K]^T.  512 thr = 8 waves (2 Mx4 N), wave tile 128x64.
//   Pipeline: tile t+3 staged (4x global_load_lds) into buf[(t+3)&3] while
//   computing tile t from buf[t&3] -> writes only touch the buffer vacated at
//   tile t-1 (race-free). Counted vmcnt: steady-state 8 outstanding loads
//   (= 2 tiles), drain 8->4->0 at tail. 2 phases/tile, 16 MFMA each, raw
//   s_barrier + setprio(1) around MFMA (T5). 64B LDS row stride => frag
//   ds_read_b128 is bank-volume-optimal, no swizzle needed.
// EPI 0: A=xn, BT=wT1 (N=4096). v=acc+b_in; gelu; col<H -> hbuf bf16 else gate f32
// EPI 1: A=shifted, BT=wT2 (N=2048). hbuf *= (acc+b_gate)
// EPI 2: A=hbuf, BT=wT3 (N=1024). fout = acc+b_out
// ============================================================================
template<int EPI>
__global__ __launch_bounds__(512, 2) void gemm256(
    const float* __restrict__ bias, float* __restrict__ fout)
{
    constexpr int K = (EPI == 0) ? D : H;
    constexpr int NT = K / 32;
    const __hip_bfloat16* __restrict__ A =
        (EPI == 0) ? ws_xn() : (EPI == 1) ? ws_shift() : ws_hbuf();
    const __hip_bfloat16* __restrict__ BT = ws_wt(EPI);

    __shared__ short smem[4][2][8192];   // [buf][A/B][256 rows x 32 cols] bf16, 128 KiB

    const int tid  = threadIdx.x;
    const int lane = tid & 63;
    const int wid  = tid >> 6;
    const int wr   = wid >> 2;           // 0..1  (M direction, 128 rows each)
    const int wc   = wid & 3;            // 0..3  (N direction, 64 cols each)
    const long bRow = (long)blockIdx.y * 256;
    const long bCol = (long)blockIdx.x * 256;

    // staging source geometry: issue covers 128 rows x 32 cols (8 KiB)
    const int s_r = tid >> 2;            // 0..127
    const int s_c = (tid & 3) << 3;      // 0,8,16,24
    const __hip_bfloat16* baseA = A  + (bRow + s_r) * (long)K + s_c;
    const __hip_bfloat16* baseB = BT + (bCol + s_r) * (long)K + s_c;
    const long stride128 = 128 * (long)K;

    auto stage_a = [&](int t) {
        short* dst = &smem[t & 3][0][tid * 8];
        gload_lds16(baseA + (long)t * 32,             (__hip_bfloat16*)dst);
        gload_lds16(baseA + (long)t * 32 + stride128, (__hip_bfloat16*)(dst + 4096));
    };
    auto stage_b = [&](int t) {
        short* dst = &smem[t & 3][1][tid * 8];
        gload_lds16(baseB + (long)t * 32,             (__hip_bfloat16*)dst);
        gload_lds16(baseB + (long)t * 32 + stride128, (__hip_bfloat16*)(dst + 4096));
    };

    // fragment read offsets (elements): row*32 + (lane>>4)*8
    const int aoff = (wr * 128 + (lane & 15)) * 32 + ((lane >> 4) << 3);
    const int boff = (wc * 64  + (lane & 15)) * 32 + ((lane >> 4) << 3);

    f32x4 acc[8][4];
    #pragma unroll
    for (int m = 0; m < 8; ++m)
        #pragma unroll
        for (int n = 0; n < 4; ++n)
            acc[m][n] = {0.f, 0.f, 0.f, 0.f};

    // prologue: stage tiles 0,1,2 (12 loads/wave); wait tile0 (8 left in flight)
    stage_a(0); stage_b(0);
    stage_a(1); stage_b(1);
    stage_a(2); stage_b(2);
    asm volatile("s_waitcnt vmcnt(8)" ::: "memory");
    phase_barrier();

    for (int t = 0; t < NT; ++t) {
        const short* bufA = smem[t & 3][0];
        const short* bufB = smem[t & 3][1];
        bf16x8 bf[4], af[4];

        // ---- phase 0: B frags + A frags m0..3, stage A of t+3 ----
        #pragma unroll
        for (int n = 0; n < 4; ++n) bf[n] = *(const bf16x8*)&bufB[boff + n * 512];
        #pragma unroll
        for (int m = 0; m < 4; ++m) af[m] = *(const bf16x8*)&bufA[aoff + m * 512];
        if (t + 3 < NT) stage_a(t + 3);
        phase_barrier();
        __builtin_amdgcn_s_setprio(1);
        #pragma unroll
        for (int m = 0; m < 4; ++m)
            #pragma unroll
            for (int n = 0; n < 4; ++n)
                acc[m][n] = __builtin_amdgcn_mfma_f32_16x16x32_bf16(af[m], bf[n], acc[m][n], 0, 0, 0);
        __builtin_amdgcn_s_setprio(0);
        phase_barrier();

        // ---- phase 1: A frags m4..7, stage B of t+3, end-of-tile vmcnt ----
        #pragma unroll
        for (int m = 0; m < 4; ++m) af[m] = *(const bf16x8*)&bufA[aoff + (m + 4) * 512];
        if (t + 3 < NT) stage_b(t + 3);
        phase_barrier();
        __builtin_amdgcn_s_setprio(1);
        #pragma unroll
        for (int m = 0; m < 4; ++m)
            #pragma unroll
            for (int n = 0; n < 4; ++n)
                acc[m + 4][n] = __builtin_amdgcn_mfma_f32_16x16x32_bf16(af[m], bf[n], acc[m + 4][n], 0, 0, 0);
        __builtin_amdgcn_s_setprio(0);
        if (t + 1 < NT) {   // ensure tile t+1 landed before its ds_reads (next iter)
            const int fly = ((NT - 1 < t + 3) ? NT - 1 : t + 3) - (t + 1);
            if (fly >= 2)      asm volatile("s_waitcnt vmcnt(8)" ::: "memory");
            else if (fly == 1) asm volatile("s_waitcnt vmcnt(4)" ::: "memory");
            else               asm volatile("s_waitcnt vmcnt(0)" ::: "memory");
        }
        phase_barrier();
    }

    // ---- epilogue ----
    __hip_bfloat16* __restrict__ hbuf = ws_hbuf();
    float* __restrict__ gate = ws_gate();
    const int lr = lane & 15;
    const int lrow4 = (lane >> 4) << 2;   // C/D: col=lane&15, row=(lane>>4)*4+r
    #pragma unroll
    for (int m = 0; m < 8; ++m) {
        #pragma unroll
        for (int n = 0; n < 4; ++n) {
            const long col = bCol + wc * 64 + n * 16 + lr;
            const float bv = bias[col];
            #pragma unroll
            for (int r = 0; r < 4; ++r) {
                const long row = bRow + wr * 128 + m * 16 + lrow4 + r;
                float v = acc[m][n][r] + bv;
                if constexpr (EPI == 0) {
                    const float g = 0.5f * v * (1.0f + erff(v * 0.70710678118654752f));
                    if (col < H) hbuf[row * H + col] = __float2bfloat16(g);
                    else         gate[row * H + (col - H)] = g;
                } else if constexpr (EPI == 1) {
                    const long idx = row * H + col;
                    const float hv = __bfloat162float(hbuf[idx]);
                    hbuf[idx] = __float2bfloat16(hv * v);
                } else {
                    fout[row * D + col] = v;
                }
            }
        }
    }
}

extern "C" void kernel_launch(void* const* d_in, const int* in_sizes, int n_in,
                              void* d_out, int out_size, void* d_ws, size_t ws_size,
                              hipStream_t stream) {
    const float* x      = (const float*)d_in[0];
    const float* ln_w   = (const float*)d_in[1];
    const float* ln_b   = (const float*)d_in[2];
    const float* w_in   = (const float*)d_in[3];
    const float* b_in   = (const float*)d_in[4];
    const float* gln_w  = (const float*)d_in[5];
    const float* gln_b  = (const float*)d_in[6];
    const float* w_gate = (const float*)d_in[7];
    const float* b_gate = (const float*)d_in[8];
    const float* w_out  = (const float*)d_in[9];
    const float* b_out  = (const float*)d_in[10];
    float* out = (float*)d_out;
    (void)d_ws; (void)ws_size;   // scratch lives in g_ws (module global)

    const dim3 tb(32, 8);
    transpose_bf16<<<dim3(N4 / 32, D / 32), tb, 0, stream>>>(w_in,   0, D, N4);
    transpose_bf16<<<dim3(H / 32,  H / 32), tb, 0, stream>>>(w_gate, 1, H, H);
    transpose_bf16<<<dim3(D / 32,  H / 32), tb, 0, stream>>>(w_out,  2, H, D);

    ln1024_kernel<<<M, 256, 0, stream>>>(x, ln_w, ln_b);

    gemm256<0><<<dim3(N4 / 256, M / 256), 512, 0, stream>>>(b_in, nullptr);

    ln2048_inplace<<<M, 512, 0, stream>>>(gln_w, gln_b);
    cumsum_p1<<<(B * NCH * H) / 256, 256, 0, stream>>>();
    cumsum_p2<<<(B * H) / 256, 256, 0, stream>>>();
    cumsum_p3<<<(B * NCH * H) / 256, 256, 0, stream>>>();
    shift_kernel<<<(int)(((size_t)B * S * H) / 256), 256, 0, stream>>>();

    gemm256<1><<<dim3(H / 256, M / 256), 512, 0, stream>>>(b_gate, nullptr);
    gemm256<2><<<dim3(D / 256, M / 256), 512, 0, stream>>>(b_out, out);
}

// Round 5
// 662.008 us; speedup vs baseline: 1.2395x; 1.0153x over previous
//
#include <hip/hip_runtime.h>
#include <hip/hip_bf16.h>
#include <cstdint>

typedef __attribute__((ext_vector_type(8))) short bf16x8;
typedef __attribute__((ext_vector_type(4))) float f32x4;

constexpr int B = 8, S = 2048, D = 1024, H = 2048, N4 = 4096;
constexpr int M = B * S;                 // 16384 rows
constexpr int CHUNK = 128, NCH = S / CHUNK;
constexpr float EPS_LN = 1e-5f, EPS_SHIFT = 1e-5f;

// ---------- all scratch lives in a module-level device global ----------
constexpr size_t SZ_XN    = (size_t)M * D * 2;       // LN(x) bf16
constexpr size_t SZ_HBUF  = (size_t)M * H * 2;       // h half (bf16), gated in place
constexpr size_t SZ_GATE  = (size_t)M * H * 4;       // gate fp32 -> LN -> cumsum (in place)
constexpr size_t SZ_SHIFT = (size_t)M * H * 2;       // shifted gate bf16
constexpr size_t SZ_WT1   = (size_t)N4 * D * 2;      // w_in^T  bf16
constexpr size_t SZ_WT2   = (size_t)H * H * 2;       // w_gate^T bf16
constexpr size_t SZ_WT3   = (size_t)D * H * 2;       // w_out^T bf16
constexpr size_t SZ_PART  = (size_t)B * NCH * H * 4; // cumsum partials

constexpr size_t OFF_XN    = 0;
constexpr size_t OFF_HBUF  = OFF_XN + SZ_XN;
constexpr size_t OFF_GATE  = OFF_HBUF + SZ_HBUF;
constexpr size_t OFF_SHIFT = OFF_GATE + SZ_GATE;
constexpr size_t OFF_WT1   = OFF_SHIFT + SZ_SHIFT;
constexpr size_t OFF_WT2   = OFF_WT1 + SZ_WT1;
constexpr size_t OFF_WT3   = OFF_WT2 + SZ_WT2;
constexpr size_t OFF_PART  = OFF_WT3 + SZ_WT3;
constexpr size_t TOTAL_WS  = OFF_PART + SZ_PART;     // ~309 MiB

__device__ __attribute__((aligned(1024))) unsigned char g_ws[TOTAL_WS];

__device__ __forceinline__ __hip_bfloat16* ws_xn()     { return (__hip_bfloat16*)(g_ws + OFF_XN); }
__device__ __forceinline__ __hip_bfloat16* ws_hbuf()   { return (__hip_bfloat16*)(g_ws + OFF_HBUF); }
__device__ __forceinline__ float*          ws_gate()   { return (float*)(g_ws + OFF_GATE); }
__device__ __forceinline__ __hip_bfloat16* ws_shift()  { return (__hip_bfloat16*)(g_ws + OFF_SHIFT); }
__device__ __forceinline__ __hip_bfloat16* ws_wt(int w){
    return (__hip_bfloat16*)(g_ws + (w == 0 ? OFF_WT1 : w == 1 ? OFF_WT2 : OFF_WT3));
}
__device__ __forceinline__ float*          ws_part()   { return (float*)(g_ws + OFF_PART); }

// async global->LDS DMA, 16 B per lane (dest must be wave-uniform base + lane*16)
__device__ __forceinline__ void gload_lds16(const __hip_bfloat16* gsrc, __hip_bfloat16* ldst) {
    __builtin_amdgcn_global_load_lds(
        (const __attribute__((address_space(1))) void*)gsrc,
        (__attribute__((address_space(3))) void*)ldst, 16, 0, 0);
}

__device__ __forceinline__ void phase_barrier() {
    asm volatile("" ::: "memory");
    __builtin_amdgcn_s_barrier();
    asm volatile("" ::: "memory");
}

__device__ __forceinline__ void block_reduce2(float& s1, float& s2) {
    #pragma unroll
    for (int off = 32; off > 0; off >>= 1) {
        s1 += __shfl_xor(s1, off);
        s2 += __shfl_xor(s2, off);
    }
    __shared__ float buf[16];
    const int wid = threadIdx.x >> 6;
    const int nw = blockDim.x >> 6;
    if ((threadIdx.x & 63) == 0) { buf[wid] = s1; buf[8 + wid] = s2; }
    __syncthreads();
    if (threadIdx.x < 64) {
        float a = (threadIdx.x < nw) ? buf[threadIdx.x] : 0.f;
        float b = (threadIdx.x < nw) ? buf[8 + threadIdx.x] : 0.f;
        #pragma unroll
        for (int off = 4; off > 0; off >>= 1) { a += __shfl_xor(a, off); b += __shfl_xor(b, off); }
        if (threadIdx.x == 0) { buf[0] = a; buf[8] = b; }
    }
    __syncthreads();
    s1 = buf[0]; s2 = buf[8];
}

// ---- weight transpose + bf16 convert: in[R][C] fp32 -> ws[C][R] bf16 ----
__global__ __launch_bounds__(256) void transpose_bf16(
    const float* __restrict__ in, int which, int R, int C) {
    __hip_bfloat16* __restrict__ out = ws_wt(which);
    __shared__ float tile[32][33];
    const int c0 = blockIdx.x * 32, r0 = blockIdx.y * 32;
    const int tx = threadIdx.x, ty = threadIdx.y;   // block (32,8)
    #pragma unroll
    for (int j = 0; j < 4; ++j)
        tile[ty + j * 8][tx] = in[(size_t)(r0 + ty + j * 8) * C + c0 + tx];
    __syncthreads();
    #pragma unroll
    for (int j = 0; j < 4; ++j)
        out[(size_t)(c0 + ty + j * 8) * R + r0 + tx] = __float2bfloat16(tile[tx][ty + j * 8]);
}

// ---- LN over rows of 1024, fp32 -> bf16 (xn) ----
__global__ __launch_bounds__(256) void ln1024_kernel(
    const float* __restrict__ x, const float* __restrict__ w, const float* __restrict__ b) {
    __hip_bfloat16* __restrict__ out = ws_xn();
    const size_t row = blockIdx.x;
    const float4 v = reinterpret_cast<const float4*>(x + row * D)[threadIdx.x];
    float s = v.x + v.y + v.z + v.w;
    float q = v.x * v.x + v.y * v.y + v.z * v.z + v.w * v.w;
    block_reduce2(s, q);
    const float mu = s * (1.0f / D);
    const float var = q * (1.0f / D) - mu * mu;
    const float rs = rsqrtf(var + EPS_LN);
    const int c = threadIdx.x * 4;
    const float4 wv = reinterpret_cast<const float4*>(w)[threadIdx.x];
    const float4 bv = reinterpret_cast<const float4*>(b)[threadIdx.x];
    __hip_bfloat16* o = out + row * D + c;
    o[0] = __float2bfloat16((v.x - mu) * rs * wv.x + bv.x);
    o[1] = __float2bfloat16((v.y - mu) * rs * wv.y + bv.y);
    o[2] = __float2bfloat16((v.z - mu) * rs * wv.z + bv.z);
    o[3] = __float2bfloat16((v.w - mu) * rs * wv.w + bv.w);
}

// ---- LN over rows of 2048, fp32 in-place on gate ----
__global__ __launch_bounds__(512) void ln2048_inplace(
    const float* __restrict__ w, const float* __restrict__ b) {
    float* __restrict__ g = ws_gate();
    const size_t row = blockIdx.x;
    float4 v = reinterpret_cast<float4*>(g + row * H)[threadIdx.x];
    float s = v.x + v.y + v.z + v.w;
    float q = v.x * v.x + v.y * v.y + v.z * v.z + v.w * v.w;
    block_reduce2(s, q);
    const float mu = s * (1.0f / H);
    const float var = q * (1.0f / H) - mu * mu;
    const float rs = rsqrtf(var + EPS_LN);
    const float4 wv = reinterpret_cast<const float4*>(w)[threadIdx.x];
    const float4 bv = reinterpret_cast<const float4*>(b)[threadIdx.x];
    float4 o;
    o.x = (v.x - mu) * rs * wv.x + bv.x;
    o.y = (v.y - mu) * rs * wv.y + bv.y;
    o.z = (v.z - mu) * rs * wv.z + bv.z;
    o.w = (v.w - mu) * rs * wv.w + bv.w;
    reinterpret_cast<float4*>(g + row * H)[threadIdx.x] = o;
}

// ---- blocked cumsum along sequence, in-place on gate [B][S][H] ----
__global__ __launch_bounds__(256) void cumsum_p1() {
    const float* __restrict__ g = ws_gate();
    float* __restrict__ part = ws_part();
    const int idx = blockIdx.x * 256 + threadIdx.x;    // B*NCH*H
    const int c = idx & (H - 1);
    const int ch = (idx >> 11) & (NCH - 1);
    const int b = idx >> 15;
    const float* p = g + ((size_t)(b * S + ch * CHUNK)) * H + c;
    float s = 0.f;
    #pragma unroll 4
    for (int t = 0; t < CHUNK; ++t) s += p[(size_t)t * H];
    part[((size_t)b * NCH + ch) * H + c] = s;
}
__global__ __launch_bounds__(256) void cumsum_p2() {
    float* __restrict__ part = ws_part();
    const int idx = blockIdx.x * 256 + threadIdx.x;    // B*H
    const int c = idx & (H - 1);
    const int b = idx >> 11;
    float run = 0.f;
    for (int ch = 0; ch < NCH; ++ch) {
        const size_t o = ((size_t)b * NCH + ch) * H + c;
        const float v = part[o]; part[o] = run; run += v;
    }
}
__global__ __launch_bounds__(256) void cumsum_p3() {
    float* __restrict__ g = ws_gate();
    const float* __restrict__ part = ws_part();
    const int idx = blockIdx.x * 256 + threadIdx.x;
    const int c = idx & (H - 1);
    const int ch = (idx >> 11) & (NCH - 1);
    const int b = idx >> 15;
    float run = part[((size_t)b * NCH + ch) * H + c];
    float* p = g + ((size_t)(b * S + ch * CHUNK)) * H + c;
    for (int t = 0; t < CHUNK; ++t) { run += p[(size_t)t * H]; p[(size_t)t * H] = run; }
}

// ---- token shift from cumsum C [B][S][H] -> shifted bf16 [B][S][H] ----
__global__ __launch_bounds__(256) void shift_kernel() {
    const float* __restrict__ Cc = ws_gate();
    __hip_bfloat16* __restrict__ out = ws_shift();
    const size_t idx = (size_t)blockIdx.x * 256 + threadIdx.x;   // B*S*H
    const int c = (int)(idx & (H - 1));
    const int t = (int)((idx >> 11) & (S - 1));
    const int b = (int)(idx >> 22);
    const float* col = Cc + ((size_t)b * S) * H + c;
    const int blk = c >> 8;            // csize = 256
    float val;
    if (blk == 7) {                    // passthrough block: recover gate_n = C[t]-C[t-1]
        const float cur = col[(size_t)t * H];
        const float prev = t ? col[(size_t)(t - 1) * H] : 0.f;
        val = cur - prev;
    } else {
        const int a = 1 << blk;
        const float n1 = (t >= a)     ? col[(size_t)(t - a) * H]     : 0.f;
        const float n2 = (t >= 2 * a) ? col[(size_t)(t - 2 * a) * H] : 0.f;
        const float sd = (float)((t >= a ? t - a : 0) - (t >= 2 * a ? t - 2 * a : 0));
        val = (n1 - n2) / (sd + EPS_SHIFT);
    }
    out[idx] = __float2bfloat16(val);
}

// ============================================================================
// 256x256-tile 8-phase MFMA GEMM, BK=32, 4 LDS buffers, bank-swizzled.
//   C = A[M][K] @ BT[N][K]^T.  512 thr = 8 waves (2 Mx4 N), wave tile 128x64.
//
// LDS bank swizzle (T2 analog for 64B-stride rows): without it, a frag
// ds_read_b128 (lane = (r=lane&15, q=lane>>4), start word 16r+4q) puts each
// 16-lane q-group on only 2 start banks -> 8-way conflict (round-4 PMC:
// 1.26e7 conflicts, MfmaUtil 23%). Swizzle sigma_r(q) = q ^ ((r>>1)&3):
// start banks spread over 8 multiples of 4, residual 2-way = free (m136).
// Rule #21: DMA dest stays LINEAR; the *global source* column is
// pre-swizzled per thread, and the read side applies the same XOR, which
// collapses to a per-lane CONSTANT (rows enter reads as ..*16 + (lane&15),
// so (row>>1)&3 == (lane>>1)&3). Zero extra K-loop instructions.
//
//   Pipeline: tile t+3 staged (4x global_load_lds) into buf[(t+3)&3] while
//   computing tile t from buf[t&3]. Counted vmcnt: steady-state 8
//   outstanding (2 tiles), drain 8->4->0 at tail. 2 phases/tile, 16 MFMA
//   each, raw s_barrier + setprio(1) around MFMA (T5).
// EPI 0: A=xn, BT=wT1 (N=4096). v=acc+b_in; gelu; col<H -> hbuf bf16 else gate f32
// EPI 1: A=shifted, BT=wT2 (N=2048). hbuf *= (acc+b_gate)
// EPI 2: A=hbuf, BT=wT3 (N=1024). fout = acc+b_out
// ============================================================================
template<int EPI>
__global__ __launch_bounds__(512, 2) void gemm256(
    const float* __restrict__ bias, float* __restrict__ fout)
{
    constexpr int K = (EPI == 0) ? D : H;
    constexpr int NT = K / 32;
    const __hip_bfloat16* __restrict__ A =
        (EPI == 0) ? ws_xn() : (EPI == 1) ? ws_shift() : ws_hbuf();
    const __hip_bfloat16* __restrict__ BT = ws_wt(EPI);

    __shared__ short smem[4][2][8192];   // [buf][A/B][256 rows x 32 cols] bf16, 128 KiB

    const int tid  = threadIdx.x;
    const int lane = tid & 63;
    const int wid  = tid >> 6;
    const int wr   = wid >> 2;           // 0..1  (M direction, 128 rows each)
    const int wc   = wid & 3;            // 0..3  (N direction, 64 cols each)
    const long bRow = (long)blockIdx.y * 256;
    const long bCol = (long)blockIdx.x * 256;

    // staging: thread tid owns LDS chunk tid = (r=tid>>2, c=tid&3); source
    // column is the SWIZZLED chunk sigma_r(c) = c ^ ((r>>1)&3) = c ^ ((tid>>3)&3)
    const int s_r = tid >> 2;            // 0..127
    const int s_c = (((tid & 3) ^ ((tid >> 3) & 3)) << 3);   // pre-swizzled source col
    const __hip_bfloat16* baseA = A  + (bRow + s_r) * (long)K + s_c;
    const __hip_bfloat16* baseB = BT + (bCol + s_r) * (long)K + s_c;
    const long stride128 = 128 * (long)K;

    auto stage_a = [&](int t) {
        short* dst = &smem[t & 3][0][tid * 8];
        gload_lds16(baseA + (long)t * 32,             (__hip_bfloat16*)dst);
        gload_lds16(baseA + (long)t * 32 + stride128, (__hip_bfloat16*)(dst + 4096));
    };
    auto stage_b = [&](int t) {
        short* dst = &smem[t & 3][1][tid * 8];
        gload_lds16(baseB + (long)t * 32,             (__hip_bfloat16*)dst);
        gload_lds16(baseB + (long)t * 32 + stride128, (__hip_bfloat16*)(dst + 4096));
    };

    // fragment read offsets (elements): row*32 + swizzled 16B-chunk * 8.
    // q' = (lane>>4) ^ ((row>>1)&3) = (lane>>4) ^ ((lane>>1)&3)  (lane-const)
    const int kk  = (((lane >> 4) ^ ((lane >> 1) & 3)) << 3);
    const int aoff = (wr * 128 + (lane & 15)) * 32 + kk;
    const int boff = (wc * 64  + (lane & 15)) * 32 + kk;

    f32x4 acc[8][4];
    #pragma unroll
    for (int m = 0; m < 8; ++m)
        #pragma unroll
        for (int n = 0; n < 4; ++n)
            acc[m][n] = {0.f, 0.f, 0.f, 0.f};

    // prologue: stage tiles 0,1,2 (12 loads/wave); wait tile0 (8 left in flight)
    stage_a(0); stage_b(0);
    stage_a(1); stage_b(1);
    stage_a(2); stage_b(2);
    asm volatile("s_waitcnt vmcnt(8)" ::: "memory");
    phase_barrier();

    for (int t = 0; t < NT; ++t) {
        const short* bufA = smem[t & 3][0];
        const short* bufB = smem[t & 3][1];
        bf16x8 bf[4], af[4];

        // ---- phase 0: B frags + A frags m0..3, stage A of t+3 ----
        #pragma unroll
        for (int n = 0; n < 4; ++n) bf[n] = *(const bf16x8*)&bufB[boff + n * 512];
        #pragma unroll
        for (int m = 0; m < 4; ++m) af[m] = *(const bf16x8*)&bufA[aoff + m * 512];
        if (t + 3 < NT) stage_a(t + 3);
        phase_barrier();
        __builtin_amdgcn_s_setprio(1);
        #pragma unroll
        for (int m = 0; m < 4; ++m)
            #pragma unroll
            for (int n = 0; n < 4; ++n)
                acc[m][n] = __builtin_amdgcn_mfma_f32_16x16x32_bf16(af[m], bf[n], acc[m][n], 0, 0, 0);
        __builtin_amdgcn_s_setprio(0);
        phase_barrier();

        // ---- phase 1: A frags m4..7, stage B of t+3, end-of-tile vmcnt ----
        #pragma unroll
        for (int m = 0; m < 4; ++m) af[m] = *(const bf16x8*)&bufA[aoff + (m + 4) * 512];
        if (t + 3 < NT) stage_b(t + 3);
        phase_barrier();
        __builtin_amdgcn_s_setprio(1);
        #pragma unroll
        for (int m = 0; m < 4; ++m)
            #pragma unroll
            for (int n = 0; n < 4; ++n)
                acc[m + 4][n] = __builtin_amdgcn_mfma_f32_16x16x32_bf16(af[m], bf[n], acc[m + 4][n], 0, 0, 0);
        __builtin_amdgcn_s_setprio(0);
        if (t + 1 < NT) {   // ensure tile t+1 landed before its ds_reads (next iter)
            const int fly = ((NT - 1 < t + 3) ? NT - 1 : t + 3) - (t + 1);
            if (fly >= 2)      asm volatile("s_waitcnt vmcnt(8)" ::: "memory");
            else if (fly == 1) asm volatile("s_waitcnt vmcnt(4)" ::: "memory");
            else               asm volatile("s_waitcnt vmcnt(0)" ::: "memory");
        }
        phase_barrier();
    }

    // ---- epilogue ----
    __hip_bfloat16* __restrict__ hbuf = ws_hbuf();
    float* __restrict__ gate = ws_gate();
    const int lr = lane & 15;
    const int lrow4 = (lane >> 4) << 2;   // C/D: col=lane&15, row=(lane>>4)*4+r
    #pragma unroll
    for (int m = 0; m < 8; ++m) {
        #pragma unroll
        for (int n = 0; n < 4; ++n) {
            const long col = bCol + wc * 64 + n * 16 + lr;
            const float bv = bias[col];
            #pragma unroll
            for (int r = 0; r < 4; ++r) {
                const long row = bRow + wr * 128 + m * 16 + lrow4 + r;
                float v = acc[m][n][r] + bv;
                if constexpr (EPI == 0) {
                    const float g = 0.5f * v * (1.0f + erff(v * 0.70710678118654752f));
                    if (col < H) hbuf[row * H + col] = __float2bfloat16(g);
                    else         gate[row * H + (col - H)] = g;
                } else if constexpr (EPI == 1) {
                    const long idx = row * H + col;
                    const float hv = __bfloat162float(hbuf[idx]);
                    hbuf[idx] = __float2bfloat16(hv * v);
                } else {
                    fout[row * D + col] = v;
                }
            }
        }
    }
}

extern "C" void kernel_launch(void* const* d_in, const int* in_sizes, int n_in,
                              void* d_out, int out_size, void* d_ws, size_t ws_size,
                              hipStream_t stream) {
    const float* x      = (const float*)d_in[0];
    const float* ln_w   = (const float*)d_in[1];
    const float* ln_b   = (const float*)d_in[2];
    const float* w_in   = (const float*)d_in[3];
    const float* b_in   = (const float*)d_in[4];
    const float* gln_w  = (const float*)d_in[5];
    const float* gln_b  = (const float*)d_in[6];
    const float* w_gate = (const float*)d_in[7];
    const float* b_gate = (const float*)d_in[8];
    const float* w_out  = (const float*)d_in[9];
    const float* b_out  = (const float*)d_in[10];
    float* out = (float*)d_out;
    (void)d_ws; (void)ws_size;   // scratch lives in g_ws (module global)

    const dim3 tb(32, 8);
    transpose_bf16<<<dim3(N4 / 32, D / 32), tb, 0, stream>>>(w_in,   0, D, N4);
    transpose_bf16<<<dim3(H / 32,  H / 32), tb, 0, stream>>>(w_gate, 1, H, H);
    transpose_bf16<<<dim3(D / 32,  H / 32), tb, 0, stream>>>(w_out,  2, H, D);

    ln1024_kernel<<<M, 256, 0, stream>>>(x, ln_w, ln_b);

    gemm256<0><<<dim3(N4 / 256, M / 256), 512, 0, stream>>>(b_in, nullptr);

    ln2048_inplace<<<M, 512, 0, stream>>>(gln_w, gln_b);
    cumsum_p1<<<(B * NCH * H) / 256, 256, 0, stream>>>();
    cumsum_p2<<<(B * H) / 256, 256, 0, stream>>>();
    cumsum_p3<<<(B * NCH * H) / 256, 256, 0, stream>>>();
    shift_kernel<<<(int)(((size_t)B * S * H) / 256), 256, 0, stream>>>();

    gemm256<1><<<dim3(H / 256, M / 256), 512, 0, stream>>>(b_gate, nullptr);
    gemm256<2><<<dim3(D / 256, M / 256), 512, 0, stream>>>(b_out, out);
}

// Round 6
// 623.439 us; speedup vs baseline: 1.3162x; 1.0619x over previous
//
#include <hip/hip_runtime.h>
#include <hip/hip_bf16.h>
#include <cstdint>

typedef __attribute__((ext_vector_type(8))) short bf16x8;
typedef __attribute__((ext_vector_type(4))) float f32x4;

constexpr int B = 8, S = 2048, D = 1024, H = 2048, N4 = 4096;
constexpr int M = B * S;                 // 16384 rows
constexpr int CHUNK = 128, NCH = S / CHUNK;
constexpr float EPS_LN = 1e-5f, EPS_SHIFT = 1e-5f;

// ---------- all scratch lives in a module-level device global ----------
constexpr size_t SZ_XN    = (size_t)M * D * 2;       // LN(x) bf16
constexpr size_t SZ_HBUF  = (size_t)M * H * 2;       // h half (bf16), gated in place
constexpr size_t SZ_GATE  = (size_t)M * H * 4;       // gate fp32 -> LN -> cumsum (in place)
constexpr size_t SZ_SHIFT = (size_t)M * H * 2;       // shifted gate bf16
constexpr size_t SZ_WT1   = (size_t)N4 * D * 2;      // w_in^T  bf16
constexpr size_t SZ_WT2   = (size_t)H * H * 2;       // w_gate^T bf16
constexpr size_t SZ_WT3   = (size_t)D * H * 2;       // w_out^T bf16
constexpr size_t SZ_PART  = (size_t)B * NCH * H * 4; // cumsum partials

constexpr size_t OFF_XN    = 0;
constexpr size_t OFF_HBUF  = OFF_XN + SZ_XN;
constexpr size_t OFF_GATE  = OFF_HBUF + SZ_HBUF;
constexpr size_t OFF_SHIFT = OFF_GATE + SZ_GATE;
constexpr size_t OFF_WT1   = OFF_SHIFT + SZ_SHIFT;
constexpr size_t OFF_WT2   = OFF_WT1 + SZ_WT1;
constexpr size_t OFF_WT3   = OFF_WT2 + SZ_WT2;
constexpr size_t OFF_PART  = OFF_WT3 + SZ_WT3;
constexpr size_t TOTAL_WS  = OFF_PART + SZ_PART;     // ~309 MiB

__device__ __attribute__((aligned(1024))) unsigned char g_ws[TOTAL_WS];

__device__ __forceinline__ __hip_bfloat16* ws_xn()     { return (__hip_bfloat16*)(g_ws + OFF_XN); }
__device__ __forceinline__ __hip_bfloat16* ws_hbuf()   { return (__hip_bfloat16*)(g_ws + OFF_HBUF); }
__device__ __forceinline__ float*          ws_gate()   { return (float*)(g_ws + OFF_GATE); }
__device__ __forceinline__ __hip_bfloat16* ws_shift()  { return (__hip_bfloat16*)(g_ws + OFF_SHIFT); }
__device__ __forceinline__ __hip_bfloat16* ws_wt(int w){
    return (__hip_bfloat16*)(g_ws + (w == 0 ? OFF_WT1 : w == 1 ? OFF_WT2 : OFF_WT3));
}
__device__ __forceinline__ float*          ws_part()   { return (float*)(g_ws + OFF_PART); }

// async global->LDS DMA, 16 B per lane (dest must be wave-uniform base + lane*16)
__device__ __forceinline__ void gload_lds16(const __hip_bfloat16* gsrc, __hip_bfloat16* ldst) {
    __builtin_amdgcn_global_load_lds(
        (const __attribute__((address_space(1))) void*)gsrc,
        (__attribute__((address_space(3))) void*)ldst, 16, 0, 0);
}

__device__ __forceinline__ void phase_barrier() {
    asm volatile("" ::: "memory");
    __builtin_amdgcn_s_barrier();
    asm volatile("" ::: "memory");
}

// ---- fast exact-GeLU: 0.5v(1+erf(v/sqrt2)) with A&S 7.1.26 minimax erf ----
// |erf err| <= 1.5e-7  (~50x below bf16 rounding of h) -> output bits identical
// to erff within bf16. ~13 VALU ops, branch-free; v_rcp/v_exp are 1-instr
// transcendentals (round-5 PMC: erff epilogue = 88us VALU-busy, the real
// GEMM1 bottleneck — MFMA-busy was already at its 59us floor).
__device__ __forceinline__ float fast_gelu(float v) {
    const float x  = v * 0.70710678118654752f;
    const float ax = __builtin_fabsf(x);
    float t;
    asm("v_rcp_f32 %0, %1" : "=v"(t) : "v"(__builtin_fmaf(0.3275911f, ax, 1.0f)));
    float p = __builtin_fmaf(1.061405429f, t, -1.453152027f);
    p = __builtin_fmaf(p, t, 1.421413741f);
    p = __builtin_fmaf(p, t, -0.284496736f);
    p = __builtin_fmaf(p, t, 0.254829592f);
    p *= t;
    float e;   // e = 2^(-x*x*log2e) = exp(-x*x)
    asm("v_exp_f32 %0, %1" : "=v"(e) : "v"(ax * ax * -1.4426950408889634f));
    const float erf_abs = __builtin_fmaf(-p, e, 1.0f);
    const float erfv = (x < 0.f) ? -erf_abs : erf_abs;
    return 0.5f * v * (1.0f + erfv);
}

__device__ __forceinline__ void block_reduce2(float& s1, float& s2) {
    #pragma unroll
    for (int off = 32; off > 0; off >>= 1) {
        s1 += __shfl_xor(s1, off);
        s2 += __shfl_xor(s2, off);
    }
    __shared__ float buf[16];
    const int wid = threadIdx.x >> 6;
    const int nw = blockDim.x >> 6;
    if ((threadIdx.x & 63) == 0) { buf[wid] = s1; buf[8 + wid] = s2; }
    __syncthreads();
    if (threadIdx.x < 64) {
        float a = (threadIdx.x < nw) ? buf[threadIdx.x] : 0.f;
        float b = (threadIdx.x < nw) ? buf[8 + threadIdx.x] : 0.f;
        #pragma unroll
        for (int off = 4; off > 0; off >>= 1) { a += __shfl_xor(a, off); b += __shfl_xor(b, off); }
        if (threadIdx.x == 0) { buf[0] = a; buf[8] = b; }
    }
    __syncthreads();
    s1 = buf[0]; s2 = buf[8];
}

// ---- weight transpose + bf16 convert: in[R][C] fp32 -> ws[C][R] bf16 ----
__global__ __launch_bounds__(256) void transpose_bf16(
    const float* __restrict__ in, int which, int R, int C) {
    __hip_bfloat16* __restrict__ out = ws_wt(which);
    __shared__ float tile[32][33];
    const int c0 = blockIdx.x * 32, r0 = blockIdx.y * 32;
    const int tx = threadIdx.x, ty = threadIdx.y;   // block (32,8)
    #pragma unroll
    for (int j = 0; j < 4; ++j)
        tile[ty + j * 8][tx] = in[(size_t)(r0 + ty + j * 8) * C + c0 + tx];
    __syncthreads();
    #pragma unroll
    for (int j = 0; j < 4; ++j)
        out[(size_t)(c0 + ty + j * 8) * R + r0 + tx] = __float2bfloat16(tile[tx][ty + j * 8]);
}

// ---- LN over rows of 1024, fp32 -> bf16 (xn) ----
__global__ __launch_bounds__(256) void ln1024_kernel(
    const float* __restrict__ x, const float* __restrict__ w, const float* __restrict__ b) {
    __hip_bfloat16* __restrict__ out = ws_xn();
    const size_t row = blockIdx.x;
    const float4 v = reinterpret_cast<const float4*>(x + row * D)[threadIdx.x];
    float s = v.x + v.y + v.z + v.w;
    float q = v.x * v.x + v.y * v.y + v.z * v.z + v.w * v.w;
    block_reduce2(s, q);
    const float mu = s * (1.0f / D);
    const float var = q * (1.0f / D) - mu * mu;
    const float rs = rsqrtf(var + EPS_LN);
    const int c = threadIdx.x * 4;
    const float4 wv = reinterpret_cast<const float4*>(w)[threadIdx.x];
    const float4 bv = reinterpret_cast<const float4*>(b)[threadIdx.x];
    __hip_bfloat16* o = out + row * D + c;
    o[0] = __float2bfloat16((v.x - mu) * rs * wv.x + bv.x);
    o[1] = __float2bfloat16((v.y - mu) * rs * wv.y + bv.y);
    o[2] = __float2bfloat16((v.z - mu) * rs * wv.z + bv.z);
    o[3] = __float2bfloat16((v.w - mu) * rs * wv.w + bv.w);
}

// ---- LN over rows of 2048, fp32 in-place on gate ----
__global__ __launch_bounds__(512) void ln2048_inplace(
    const float* __restrict__ w, const float* __restrict__ b) {
    float* __restrict__ g = ws_gate();
    const size_t row = blockIdx.x;
    float4 v = reinterpret_cast<float4*>(g + row * H)[threadIdx.x];
    float s = v.x + v.y + v.z + v.w;
    float q = v.x * v.x + v.y * v.y + v.z * v.z + v.w * v.w;
    block_reduce2(s, q);
    const float mu = s * (1.0f / H);
    const float var = q * (1.0f / H) - mu * mu;
    const float rs = rsqrtf(var + EPS_LN);
    const float4 wv = reinterpret_cast<const float4*>(w)[threadIdx.x];
    const float4 bv = reinterpret_cast<const float4*>(b)[threadIdx.x];
    float4 o;
    o.x = (v.x - mu) * rs * wv.x + bv.x;
    o.y = (v.y - mu) * rs * wv.y + bv.y;
    o.z = (v.z - mu) * rs * wv.z + bv.z;
    o.w = (v.w - mu) * rs * wv.w + bv.w;
    reinterpret_cast<float4*>(g + row * H)[threadIdx.x] = o;
}

// ---- blocked cumsum along sequence, in-place on gate [B][S][H] ----
__global__ __launch_bounds__(256) void cumsum_p1() {
    const float* __restrict__ g = ws_gate();
    float* __restrict__ part = ws_part();
    const int idx = blockIdx.x * 256 + threadIdx.x;    // B*NCH*H
    const int c = idx & (H - 1);
    const int ch = (idx >> 11) & (NCH - 1);
    const int b = idx >> 15;
    const float* p = g + ((size_t)(b * S + ch * CHUNK)) * H + c;
    float s = 0.f;
    #pragma unroll 4
    for (int t = 0; t < CHUNK; ++t) s += p[(size_t)t * H];
    part[((size_t)b * NCH + ch) * H + c] = s;
}
__global__ __launch_bounds__(256) void cumsum_p2() {
    float* __restrict__ part = ws_part();
    const int idx = blockIdx.x * 256 + threadIdx.x;    // B*H
    const int c = idx & (H - 1);
    const int b = idx >> 11;
    float run = 0.f;
    for (int ch = 0; ch < NCH; ++ch) {
        const size_t o = ((size_t)b * NCH + ch) * H + c;
        const float v = part[o]; part[o] = run; run += v;
    }
}
__global__ __launch_bounds__(256) void cumsum_p3() {
    float* __restrict__ g = ws_gate();
    const float* __restrict__ part = ws_part();
    const int idx = blockIdx.x * 256 + threadIdx.x;
    const int c = idx & (H - 1);
    const int ch = (idx >> 11) & (NCH - 1);
    const int b = idx >> 15;
    float run = part[((size_t)b * NCH + ch) * H + c];
    float* p = g + ((size_t)(b * S + ch * CHUNK)) * H + c;
    for (int t = 0; t < CHUNK; ++t) { run += p[(size_t)t * H]; p[(size_t)t * H] = run; }
}

// ---- token shift from cumsum C [B][S][H] -> shifted bf16 [B][S][H] ----
__global__ __launch_bounds__(256) void shift_kernel() {
    const float* __restrict__ Cc = ws_gate();
    __hip_bfloat16* __restrict__ out = ws_shift();
    const size_t idx = (size_t)blockIdx.x * 256 + threadIdx.x;   // B*S*H
    const int c = (int)(idx & (H - 1));
    const int t = (int)((idx >> 11) & (S - 1));
    const int b = (int)(idx >> 22);
    const float* col = Cc + ((size_t)b * S) * H + c;
    const int blk = c >> 8;            // csize = 256
    float val;
    if (blk == 7) {                    // passthrough block: recover gate_n = C[t]-C[t-1]
        const float cur = col[(size_t)t * H];
        const float prev = t ? col[(size_t)(t - 1) * H] : 0.f;
        val = cur - prev;
    } else {
        const int a = 1 << blk;
        const float n1 = (t >= a)     ? col[(size_t)(t - a) * H]     : 0.f;
        const float n2 = (t >= 2 * a) ? col[(size_t)(t - 2 * a) * H] : 0.f;
        const float sd = (float)((t >= a ? t - a : 0) - (t >= 2 * a ? t - 2 * a : 0));
        val = (n1 - n2) / (sd + EPS_SHIFT);
    }
    out[idx] = __float2bfloat16(val);
}

// ============================================================================
// 256x256-tile 8-phase MFMA GEMM, BK=32, 4 LDS buffers, bank-swizzled
// (swizzle verified: SQ_LDS_BANK_CONFLICT = 0 in round 5).
// See round-5 comments for swizzle derivation and pipeline proof.
// EPI 0: A=xn, BT=wT1 (N=4096). v=acc+b_in; gelu; col<H -> hbuf bf16 else gate f32
// EPI 1: A=shifted, BT=wT2 (N=2048). hbuf *= (acc+b_gate)
// EPI 2: A=hbuf, BT=wT3 (N=1024). fout = acc+b_out
// ============================================================================
template<int EPI>
__global__ __launch_bounds__(512, 2) void gemm256(
    const float* __restrict__ bias, float* __restrict__ fout)
{
    constexpr int K = (EPI == 0) ? D : H;
    constexpr int NT = K / 32;
    const __hip_bfloat16* __restrict__ A =
        (EPI == 0) ? ws_xn() : (EPI == 1) ? ws_shift() : ws_hbuf();
    const __hip_bfloat16* __restrict__ BT = ws_wt(EPI);

    __shared__ short smem[4][2][8192];   // [buf][A/B][256 rows x 32 cols] bf16, 128 KiB

    const int tid  = threadIdx.x;
    const int lane = tid & 63;
    const int wid  = tid >> 6;
    const int wr   = wid >> 2;           // 0..1  (M direction, 128 rows each)
    const int wc   = wid & 3;            // 0..3  (N direction, 64 cols each)
    const long bRow = (long)blockIdx.y * 256;
    const long bCol = (long)blockIdx.x * 256;

    // staging: thread tid owns LDS chunk tid = (r=tid>>2, c=tid&3); source
    // column is the SWIZZLED chunk sigma_r(c) = c ^ ((r>>1)&3) = c ^ ((tid>>3)&3)
    const int s_r = tid >> 2;            // 0..127
    const int s_c = (((tid & 3) ^ ((tid >> 3) & 3)) << 3);   // pre-swizzled source col
    const __hip_bfloat16* baseA = A  + (bRow + s_r) * (long)K + s_c;
    const __hip_bfloat16* baseB = BT + (bCol + s_r) * (long)K + s_c;
    const long stride128 = 128 * (long)K;

    auto stage_a = [&](int t) {
        short* dst = &smem[t & 3][0][tid * 8];
        gload_lds16(baseA + (long)t * 32,             (__hip_bfloat16*)dst);
        gload_lds16(baseA + (long)t * 32 + stride128, (__hip_bfloat16*)(dst + 4096));
    };
    auto stage_b = [&](int t) {
        short* dst = &smem[t & 3][1][tid * 8];
        gload_lds16(baseB + (long)t * 32,             (__hip_bfloat16*)dst);
        gload_lds16(baseB + (long)t * 32 + stride128, (__hip_bfloat16*)(dst + 4096));
    };

    // fragment read offsets (elements): row*32 + swizzled 16B-chunk * 8.
    // q' = (lane>>4) ^ ((row>>1)&3) = (lane>>4) ^ ((lane>>1)&3)  (lane-const)
    const int kk  = (((lane >> 4) ^ ((lane >> 1) & 3)) << 3);
    const int aoff = (wr * 128 + (lane & 15)) * 32 + kk;
    const int boff = (wc * 64  + (lane & 15)) * 32 + kk;

    f32x4 acc[8][4];
    #pragma unroll
    for (int m = 0; m < 8; ++m)
        #pragma unroll
        for (int n = 0; n < 4; ++n)
            acc[m][n] = {0.f, 0.f, 0.f, 0.f};

    // prologue: stage tiles 0,1,2 (12 loads/wave); wait tile0 (8 left in flight)
    stage_a(0); stage_b(0);
    stage_a(1); stage_b(1);
    stage_a(2); stage_b(2);
    asm volatile("s_waitcnt vmcnt(8)" ::: "memory");
    phase_barrier();

    for (int t = 0; t < NT; ++t) {
        const short* bufA = smem[t & 3][0];
        const short* bufB = smem[t & 3][1];
        bf16x8 bf[4], af[4];

        // ---- phase 0: B frags + A frags m0..3, stage A of t+3 ----
        #pragma unroll
        for (int n = 0; n < 4; ++n) bf[n] = *(const bf16x8*)&bufB[boff + n * 512];
        #pragma unroll
        for (int m = 0; m < 4; ++m) af[m] = *(const bf16x8*)&bufA[aoff + m * 512];
        if (t + 3 < NT) stage_a(t + 3);
        phase_barrier();
        __builtin_amdgcn_s_setprio(1);
        #pragma unroll
        for (int m = 0; m < 4; ++m)
            #pragma unroll
            for (int n = 0; n < 4; ++n)
                acc[m][n] = __builtin_amdgcn_mfma_f32_16x16x32_bf16(af[m], bf[n], acc[m][n], 0, 0, 0);
        __builtin_amdgcn_s_setprio(0);
        phase_barrier();

        // ---- phase 1: A frags m4..7, stage B of t+3, end-of-tile vmcnt ----
        #pragma unroll
        for (int m = 0; m < 4; ++m) af[m] = *(const bf16x8*)&bufA[aoff + (m + 4) * 512];
        if (t + 3 < NT) stage_b(t + 3);
        phase_barrier();
        __builtin_amdgcn_s_setprio(1);
        #pragma unroll
        for (int m = 0; m < 4; ++m)
            #pragma unroll
            for (int n = 0; n < 4; ++n)
                acc[m + 4][n] = __builtin_amdgcn_mfma_f32_16x16x32_bf16(af[m], bf[n], acc[m + 4][n], 0, 0, 0);
        __builtin_amdgcn_s_setprio(0);
        if (t + 1 < NT) {   // ensure tile t+1 landed before its ds_reads (next iter)
            const int fly = ((NT - 1 < t + 3) ? NT - 1 : t + 3) - (t + 1);
            if (fly >= 2)      asm volatile("s_waitcnt vmcnt(8)" ::: "memory");
            else if (fly == 1) asm volatile("s_waitcnt vmcnt(4)" ::: "memory");
            else               asm volatile("s_waitcnt vmcnt(0)" ::: "memory");
        }
        phase_barrier();
    }

    // ---- epilogue ----
    __hip_bfloat16* __restrict__ hbuf = ws_hbuf();
    float* __restrict__ gate = ws_gate();
    const int lr = lane & 15;
    const int lrow4 = (lane >> 4) << 2;   // C/D: col=lane&15, row=(lane>>4)*4+r
    #pragma unroll
    for (int m = 0; m < 8; ++m) {
        #pragma unroll
        for (int n = 0; n < 4; ++n) {
            const long col = bCol + wc * 64 + n * 16 + lr;
            const float bv = bias[col];
            #pragma unroll
            for (int r = 0; r < 4; ++r) {
                const long row = bRow + wr * 128 + m * 16 + lrow4 + r;
                float v = acc[m][n][r] + bv;
                if constexpr (EPI == 0) {
                    const float g = fast_gelu(v);
                    if (col < H) hbuf[row * H + col] = __float2bfloat16(g);
                    else         gate[row * H + (col - H)] = g;
                } else if constexpr (EPI == 1) {
                    const long idx = row * H + col;
                    const float hv = __bfloat162float(hbuf[idx]);
                    hbuf[idx] = __float2bfloat16(hv * v);
                } else {
                    fout[row * D + col] = v;
                }
            }
        }
    }
}

extern "C" void kernel_launch(void* const* d_in, const int* in_sizes, int n_in,
                              void* d_out, int out_size, void* d_ws, size_t ws_size,
                              hipStream_t stream) {
    const float* x      = (const float*)d_in[0];
    const float* ln_w   = (const float*)d_in[1];
    const float* ln_b   = (const float*)d_in[2];
    const float* w_in   = (const float*)d_in[3];
    const float* b_in   = (const float*)d_in[4];
    const float* gln_w  = (const float*)d_in[5];
    const float* gln_b  = (const float*)d_in[6];
    const float* w_gate = (const float*)d_in[7];
    const float* b_gate = (const float*)d_in[8];
    const float* w_out  = (const float*)d_in[9];
    const float* b_out  = (const float*)d_in[10];
    float* out = (float*)d_out;
    (void)d_ws; (void)ws_size;   // scratch lives in g_ws (module global)

    const dim3 tb(32, 8);
    transpose_bf16<<<dim3(N4 / 32, D / 32), tb, 0, stream>>>(w_in,   0, D, N4);
    transpose_bf16<<<dim3(H / 32,  H / 32), tb, 0, stream>>>(w_gate, 1, H, H);
    transpose_bf16<<<dim3(D / 32,  H / 32), tb, 0, stream>>>(w_out,  2, H, D);

    ln1024_kernel<<<M, 256, 0, stream>>>(x, ln_w, ln_b);

    gemm256<0><<<dim3(N4 / 256, M / 256), 512, 0, stream>>>(b_in, nullptr);

    ln2048_inplace<<<M, 512, 0, stream>>>(gln_w, gln_b);
    cumsum_p1<<<(B * NCH * H) / 256, 256, 0, stream>>>();
    cumsum_p2<<<(B * H) / 256, 256, 0, stream>>>();
    cumsum_p3<<<(B * NCH * H) / 256, 256, 0, stream>>>();
    shift_kernel<<<(int)(((size_t)B * S * H) / 256), 256, 0, stream>>>();

    gemm256<1><<<dim3(H / 256, M / 256), 512, 0, stream>>>(b_gate, nullptr);
    gemm256<2><<<dim3(D / 256, M / 256), 512, 0, stream>>>(b_out, out);
}

// Round 7
// 600.234 us; speedup vs baseline: 1.3671x; 1.0387x over previous
//
#include <hip/hip_runtime.h>
#include <hip/hip_bf16.h>
#include <cstdint>

typedef __attribute__((ext_vector_type(8))) short bf16x8;
typedef __attribute__((ext_vector_type(4))) float f32x4;

constexpr int B = 8, S = 2048, D = 1024, H = 2048, N4 = 4096;
constexpr int M = B * S;                 // 16384 rows
constexpr int CHUNK = 128, NCH = S / CHUNK;
constexpr float EPS_LN = 1e-5f, EPS_SHIFT = 1e-5f;

// ---------- all scratch lives in a module-level device global ----------
constexpr size_t SZ_XN     = (size_t)M * D * 2;       // LN(x) bf16
constexpr size_t SZ_HBUF   = (size_t)M * H * 2;       // h half (bf16), gated in place
constexpr size_t SZ_CSUM   = (size_t)M * H * 4;       // fp32 cumsum of LN'd gate
constexpr size_t SZ_SHIFT  = (size_t)M * H * 2;       // shifted gate bf16
constexpr size_t SZ_WT1    = (size_t)N4 * D * 2;      // w_in^T  bf16
constexpr size_t SZ_WT2    = (size_t)H * H * 2;       // w_gate^T bf16
constexpr size_t SZ_WT3    = (size_t)D * H * 2;       // w_out^T bf16
constexpr size_t SZ_PART   = (size_t)B * NCH * H * 4; // cumsum partials
constexpr size_t SZ_GATEBF = (size_t)M * H * 2;       // raw gelu gate bf16 (GEMM1 out)
constexpr size_t SZ_STATS  = (size_t)M * 8;           // per-row (mu, rsig) float2

constexpr size_t OFF_XN     = 0;
constexpr size_t OFF_HBUF   = OFF_XN + SZ_XN;
constexpr size_t OFF_CSUM   = OFF_HBUF + SZ_HBUF;
constexpr size_t OFF_SHIFT  = OFF_CSUM + SZ_CSUM;
constexpr size_t OFF_WT1    = OFF_SHIFT + SZ_SHIFT;
constexpr size_t OFF_WT2    = OFF_WT1 + SZ_WT1;
constexpr size_t OFF_WT3    = OFF_WT2 + SZ_WT2;
constexpr size_t OFF_PART   = OFF_WT3 + SZ_WT3;
constexpr size_t OFF_GATEBF = OFF_PART + SZ_PART;
constexpr size_t OFF_STATS  = OFF_GATEBF + SZ_GATEBF;
constexpr size_t TOTAL_WS   = OFF_STATS + SZ_STATS;   // ~373 MiB

__device__ __attribute__((aligned(1024))) unsigned char g_ws[TOTAL_WS];

__device__ __forceinline__ __hip_bfloat16* ws_xn()     { return (__hip_bfloat16*)(g_ws + OFF_XN); }
__device__ __forceinline__ __hip_bfloat16* ws_hbuf()   { return (__hip_bfloat16*)(g_ws + OFF_HBUF); }
__device__ __forceinline__ float*          ws_csum()   { return (float*)(g_ws + OFF_CSUM); }
__device__ __forceinline__ __hip_bfloat16* ws_shift()  { return (__hip_bfloat16*)(g_ws + OFF_SHIFT); }
__device__ __forceinline__ __hip_bfloat16* ws_wt(int w){
    return (__hip_bfloat16*)(g_ws + (w == 0 ? OFF_WT1 : w == 1 ? OFF_WT2 : OFF_WT3));
}
__device__ __forceinline__ float*          ws_part()   { return (float*)(g_ws + OFF_PART); }
__device__ __forceinline__ __hip_bfloat16* ws_gatebf() { return (__hip_bfloat16*)(g_ws + OFF_GATEBF); }
__device__ __forceinline__ float2*         ws_stats()  { return (float2*)(g_ws + OFF_STATS); }

// async global->LDS DMA, 16 B per lane (dest must be wave-uniform base + lane*16)
__device__ __forceinline__ void gload_lds16(const __hip_bfloat16* gsrc, __hip_bfloat16* ldst) {
    __builtin_amdgcn_global_load_lds(
        (const __attribute__((address_space(1))) void*)gsrc,
        (__attribute__((address_space(3))) void*)ldst, 16, 0, 0);
}

__device__ __forceinline__ void phase_barrier() {
    asm volatile("" ::: "memory");
    __builtin_amdgcn_s_barrier();
    asm volatile("" ::: "memory");
}

__device__ __forceinline__ float bfbits2f(short u) {
    unsigned int x = ((unsigned int)(unsigned short)u) << 16;
    union { unsigned int i; float f; } cv; cv.i = x; return cv.f;
}

// ---- fast exact-GeLU (A&S 7.1.26 minimax erf, |err|<=1.5e-7) ----
__device__ __forceinline__ float fast_gelu(float v) {
    const float x  = v * 0.70710678118654752f;
    const float ax = __builtin_fabsf(x);
    float t;
    asm("v_rcp_f32 %0, %1" : "=v"(t) : "v"(__builtin_fmaf(0.3275911f, ax, 1.0f)));
    float p = __builtin_fmaf(1.061405429f, t, -1.453152027f);
    p = __builtin_fmaf(p, t, 1.421413741f);
    p = __builtin_fmaf(p, t, -0.284496736f);
    p = __builtin_fmaf(p, t, 0.254829592f);
    p *= t;
    float e;   // exp(-x*x)
    asm("v_exp_f32 %0, %1" : "=v"(e) : "v"(ax * ax * -1.4426950408889634f));
    const float erf_abs = __builtin_fmaf(-p, e, 1.0f);
    const float erfv = (x < 0.f) ? -erf_abs : erf_abs;
    return 0.5f * v * (1.0f + erfv);
}

__device__ __forceinline__ void block_reduce2(float& s1, float& s2) {
    #pragma unroll
    for (int off = 32; off > 0; off >>= 1) {
        s1 += __shfl_xor(s1, off);
        s2 += __shfl_xor(s2, off);
    }
    __shared__ float buf[16];
    const int wid = threadIdx.x >> 6;
    const int nw = blockDim.x >> 6;
    if ((threadIdx.x & 63) == 0) { buf[wid] = s1; buf[8 + wid] = s2; }
    __syncthreads();
    if (threadIdx.x < 64) {
        float a = (threadIdx.x < nw) ? buf[threadIdx.x] : 0.f;
        float b = (threadIdx.x < nw) ? buf[8 + threadIdx.x] : 0.f;
        #pragma unroll
        for (int off = 4; off > 0; off >>= 1) { a += __shfl_xor(a, off); b += __shfl_xor(b, off); }
        if (threadIdx.x == 0) { buf[0] = a; buf[8] = b; }
    }
    __syncthreads();
    s1 = buf[0]; s2 = buf[8];
}

// ---- weight transpose + bf16 convert: in[R][C] fp32 -> ws[C][R] bf16 ----
__global__ __launch_bounds__(256) void transpose_bf16(
    const float* __restrict__ in, int which, int R, int C) {
    __hip_bfloat16* __restrict__ out = ws_wt(which);
    __shared__ float tile[32][33];
    const int c0 = blockIdx.x * 32, r0 = blockIdx.y * 32;
    const int tx = threadIdx.x, ty = threadIdx.y;   // block (32,8)
    #pragma unroll
    for (int j = 0; j < 4; ++j)
        tile[ty + j * 8][tx] = in[(size_t)(r0 + ty + j * 8) * C + c0 + tx];
    __syncthreads();
    #pragma unroll
    for (int j = 0; j < 4; ++j)
        out[(size_t)(c0 + ty + j * 8) * R + r0 + tx] = __float2bfloat16(tile[tx][ty + j * 8]);
}

// ---- LN over rows of 1024, fp32 -> bf16 (xn) ----
__global__ __launch_bounds__(256) void ln1024_kernel(
    const float* __restrict__ x, const float* __restrict__ w, const float* __restrict__ b) {
    __hip_bfloat16* __restrict__ out = ws_xn();
    const size_t row = blockIdx.x;
    const float4 v = reinterpret_cast<const float4*>(x + row * D)[threadIdx.x];
    float s = v.x + v.y + v.z + v.w;
    float q = v.x * v.x + v.y * v.y + v.z * v.z + v.w * v.w;
    block_reduce2(s, q);
    const float mu = s * (1.0f / D);
    const float var = q * (1.0f / D) - mu * mu;
    const float rs = rsqrtf(var + EPS_LN);
    const int c = threadIdx.x * 4;
    const float4 wv = reinterpret_cast<const float4*>(w)[threadIdx.x];
    const float4 bv = reinterpret_cast<const float4*>(b)[threadIdx.x];
    __hip_bfloat16* o = out + row * D + c;
    o[0] = __float2bfloat16((v.x - mu) * rs * wv.x + bv.x);
    o[1] = __float2bfloat16((v.y - mu) * rs * wv.y + bv.y);
    o[2] = __float2bfloat16((v.z - mu) * rs * wv.z + bv.z);
    o[3] = __float2bfloat16((v.w - mu) * rs * wv.w + bv.w);
}

// ---- per-row LN stats of gate (bf16 in, float2 (mu, rsig) out) ----
__global__ __launch_bounds__(256) void ln2048_stats() {
    const __hip_bfloat16* __restrict__ g = ws_gatebf();
    const size_t row = blockIdx.x;
    const bf16x8 v = *(const bf16x8*)(g + row * H + threadIdx.x * 8);
    float s = 0.f, q = 0.f;
    #pragma unroll
    for (int j = 0; j < 8; ++j) { const float f = bfbits2f(v[j]); s += f; q += f * f; }
    block_reduce2(s, q);
    if (threadIdx.x == 0) {
        const float mu = s * (1.0f / H);
        const float var = q * (1.0f / H) - mu * mu;
        ws_stats()[row] = make_float2(mu, rsqrtf(var + EPS_LN));
    }
}

// ---- blocked cumsum over LN(gate): p1 chunk sums, p2 prefix, p3 full ----
// LN applied on the fly: val = (g - mu)*rsig*gw[c] + gb[c]
__global__ __launch_bounds__(256) void cumsum_p1(
    const float* __restrict__ gw, const float* __restrict__ gb) {
    const int idx = blockIdx.x * 256 + threadIdx.x;    // B*NCH*H
    const int c = idx & (H - 1);
    const int ch = (idx >> 11) & (NCH - 1);
    const int b = idx >> 15;
    const int row0 = b * S + ch * CHUNK;
    const __hip_bfloat16* p = ws_gatebf() + (size_t)row0 * H + c;
    const float2* st = ws_stats() + row0;
    const float wv = gw[c], bv = gb[c];
    float s = 0.f;
    #pragma unroll 4
    for (int t = 0; t < CHUNK; ++t) {
        const float g = __bfloat162float(p[(size_t)t * H]);
        const float2 mr = st[t];
        s += (g - mr.x) * mr.y * wv + bv;
    }
    ws_part()[((size_t)b * NCH + ch) * H + c] = s;
}
__global__ __launch_bounds__(256) void cumsum_p2() {
    float* __restrict__ part = ws_part();
    const int idx = blockIdx.x * 256 + threadIdx.x;    // B*H
    const int c = idx & (H - 1);
    const int b = idx >> 11;
    float run = 0.f;
    for (int ch = 0; ch < NCH; ++ch) {
        const size_t o = ((size_t)b * NCH + ch) * H + c;
        const float v = part[o]; part[o] = run; run += v;
    }
}
__global__ __launch_bounds__(256) void cumsum_p3(
    const float* __restrict__ gw, const float* __restrict__ gb) {
    const int idx = blockIdx.x * 256 + threadIdx.x;
    const int c = idx & (H - 1);
    const int ch = (idx >> 11) & (NCH - 1);
    const int b = idx >> 15;
    const int row0 = b * S + ch * CHUNK;
    const __hip_bfloat16* p = ws_gatebf() + (size_t)row0 * H + c;
    const float2* st = ws_stats() + row0;
    float* cs = ws_csum() + (size_t)row0 * H + c;
    const float wv = gw[c], bv = gb[c];
    float run = ws_part()[((size_t)b * NCH + ch) * H + c];
    for (int t = 0; t < CHUNK; ++t) {
        const float g = __bfloat162float(p[(size_t)t * H]);
        const float2 mr = st[t];
        run += (g - mr.x) * mr.y * wv + bv;
        cs[(size_t)t * H] = run;
    }
}

// ---- token shift from cumsum C [B][S][H] -> shifted bf16 [B][S][H] ----
__global__ __launch_bounds__(256) void shift_kernel() {
    const float* __restrict__ Cc = ws_csum();
    __hip_bfloat16* __restrict__ out = ws_shift();
    const size_t idx = (size_t)blockIdx.x * 256 + threadIdx.x;   // B*S*H
    const int c = (int)(idx & (H - 1));
    const int t = (int)((idx >> 11) & (S - 1));
    const int b = (int)(idx >> 22);
    const float* col = Cc + ((size_t)b * S) * H + c;
    const int blk = c >> 8;            // csize = 256
    float val;
    if (blk == 7) {                    // passthrough block: recover gate_n = C[t]-C[t-1]
        const float cur = col[(size_t)t * H];
        const float prev = t ? col[(size_t)(t - 1) * H] : 0.f;
        val = cur - prev;
    } else {
        const int a = 1 << blk;
        const float n1 = (t >= a)     ? col[(size_t)(t - a) * H]     : 0.f;
        const float n2 = (t >= 2 * a) ? col[(size_t)(t - 2 * a) * H] : 0.f;
        const float sd = (float)((t >= a ? t - a : 0) - (t >= 2 * a ? t - 2 * a : 0));
        val = (n1 - n2) / (sd + EPS_SHIFT);
    }
    out[idx] = __float2bfloat16(val);
}

// ============================================================================
// 256x256-tile 8-phase MFMA GEMM, BK=32, 4 LDS buffers, bank-swizzled
// (swizzle verified: SQ_LDS_BANK_CONFLICT = 0 since round 5) + T1 XCD swizzle.
// EPI 0: A=xn, BT=wT1 (N=4096). v=acc+b_in; gelu; col<H -> hbuf bf16 else gatebf bf16
// EPI 1: A=shifted, BT=wT2 (N=2048). hbuf *= (acc+b_gate)
// EPI 2: A=hbuf, BT=wT3 (N=1024). fout = acc+b_out
// ============================================================================
template<int EPI>
__global__ __launch_bounds__(512, 2) void gemm256(
    const float* __restrict__ bias, float* __restrict__ fout)
{
    constexpr int K = (EPI == 0) ? D : H;
    constexpr int NT = K / 32;
    const __hip_bfloat16* __restrict__ A =
        (EPI == 0) ? ws_xn() : (EPI == 1) ? ws_shift() : ws_hbuf();
    const __hip_bfloat16* __restrict__ BT = ws_wt(EPI);

    __shared__ short smem[4][2][8192];   // [buf][A/B][256 rows x 32 cols] bf16, 128 KiB

    const int tid  = threadIdx.x;
    const int lane = tid & 63;
    const int wid  = tid >> 6;
    const int wr   = wid >> 2;           // 0..1  (M direction, 128 rows each)
    const int wc   = wid & 3;            // 0..3  (N direction, 64 cols each)

    // T1: XCD-aware block swizzle (nwg % 8 == 0 for all three GEMMs).
    // XCD k (bids == k mod 8) gets a contiguous chunk of row-panels -> A-panel
    // L2 reuse within an XCD instead of 8-way L2 thrash.
    const int nbx = gridDim.x;
    const int nwg = nbx * gridDim.y;
    const int bid = blockIdx.y * nbx + blockIdx.x;
    const int swz = (bid & 7) * (nwg >> 3) + (bid >> 3);
    const long bRow = (long)(swz / nbx) * 256;
    const long bCol = (long)(swz % nbx) * 256;

    // staging: thread tid owns LDS chunk tid = (r=tid>>2, c=tid&3); source
    // column is the SWIZZLED chunk sigma_r(c) = c ^ ((r>>1)&3) = c ^ ((tid>>3)&3)
    const int s_r = tid >> 2;            // 0..127
    const int s_c = (((tid & 3) ^ ((tid >> 3) & 3)) << 3);   // pre-swizzled source col
    const __hip_bfloat16* baseA = A  + (bRow + s_r) * (long)K + s_c;
    const __hip_bfloat16* baseB = BT + (bCol + s_r) * (long)K + s_c;
    const long stride128 = 128 * (long)K;

    auto stage_a = [&](int t) {
        short* dst = &smem[t & 3][0][tid * 8];
        gload_lds16(baseA + (long)t * 32,             (__hip_bfloat16*)dst);
        gload_lds16(baseA + (long)t * 32 + stride128, (__hip_bfloat16*)(dst + 4096));
    };
    auto stage_b = [&](int t) {
        short* dst = &smem[t & 3][1][tid * 8];
        gload_lds16(baseB + (long)t * 32,             (__hip_bfloat16*)dst);
        gload_lds16(baseB + (long)t * 32 + stride128, (__hip_bfloat16*)(dst + 4096));
    };

    // fragment read offsets (elements): row*32 + swizzled 16B-chunk * 8.
    const int kk  = (((lane >> 4) ^ ((lane >> 1) & 3)) << 3);
    const int aoff = (wr * 128 + (lane & 15)) * 32 + kk;
    const int boff = (wc * 64  + (lane & 15)) * 32 + kk;

    f32x4 acc[8][4];
    #pragma unroll
    for (int m = 0; m < 8; ++m)
        #pragma unroll
        for (int n = 0; n < 4; ++n)
            acc[m][n] = {0.f, 0.f, 0.f, 0.f};

    // prologue: stage tiles 0,1,2 (12 loads/wave); wait tile0 (8 left in flight)
    stage_a(0); stage_b(0);
    stage_a(1); stage_b(1);
    stage_a(2); stage_b(2);
    asm volatile("s_waitcnt vmcnt(8)" ::: "memory");
    phase_barrier();

    for (int t = 0; t < NT; ++t) {
        const short* bufA = smem[t & 3][0];
        const short* bufB = smem[t & 3][1];
        bf16x8 bf[4], af[4];

        // ---- phase 0: B frags + A frags m0..3, stage A of t+3 ----
        #pragma unroll
        for (int n = 0; n < 4; ++n) bf[n] = *(const bf16x8*)&bufB[boff + n * 512];
        #pragma unroll
        for (int m = 0; m < 4; ++m) af[m] = *(const bf16x8*)&bufA[aoff + m * 512];
        if (t + 3 < NT) stage_a(t + 3);
        phase_barrier();
        __builtin_amdgcn_s_setprio(1);
        #pragma unroll
        for (int m = 0; m < 4; ++m)
            #pragma unroll
            for (int n = 0; n < 4; ++n)
                acc[m][n] = __builtin_amdgcn_mfma_f32_16x16x32_bf16(af[m], bf[n], acc[m][n], 0, 0, 0);
        __builtin_amdgcn_s_setprio(0);
        phase_barrier();

        // ---- phase 1: A frags m4..7, stage B of t+3, end-of-tile vmcnt ----
        #pragma unroll
        for (int m = 0; m < 4; ++m) af[m] = *(const bf16x8*)&bufA[aoff + (m + 4) * 512];
        if (t + 3 < NT) stage_b(t + 3);
        phase_barrier();
        __builtin_amdgcn_s_setprio(1);
        #pragma unroll
        for (int m = 0; m < 4; ++m)
            #pragma unroll
            for (int n = 0; n < 4; ++n)
                acc[m + 4][n] = __builtin_amdgcn_mfma_f32_16x16x32_bf16(af[m], bf[n], acc[m + 4][n], 0, 0, 0);
        __builtin_amdgcn_s_setprio(0);
        if (t + 1 < NT) {   // ensure tile t+1 landed before its ds_reads (next iter)
            const int fly = ((NT - 1 < t + 3) ? NT - 1 : t + 3) - (t + 1);
            if (fly >= 2)      asm volatile("s_waitcnt vmcnt(8)" ::: "memory");
            else if (fly == 1) asm volatile("s_waitcnt vmcnt(4)" ::: "memory");
            else               asm volatile("s_waitcnt vmcnt(0)" ::: "memory");
        }
        phase_barrier();
    }

    // ---- epilogue ----
    __hip_bfloat16* __restrict__ hbuf = ws_hbuf();
    __hip_bfloat16* __restrict__ gatebf = ws_gatebf();
    const int lr = lane & 15;
    const int lrow4 = (lane >> 4) << 2;   // C/D: col=lane&15, row=(lane>>4)*4+r
    #pragma unroll
    for (int m = 0; m < 8; ++m) {
        #pragma unroll
        for (int n = 0; n < 4; ++n) {
            const long col = bCol + wc * 64 + n * 16 + lr;
            const float bv = bias[col];
            #pragma unroll
            for (int r = 0; r < 4; ++r) {
                const long row = bRow + wr * 128 + m * 16 + lrow4 + r;
                float v = acc[m][n][r] + bv;
                if constexpr (EPI == 0) {
                    const float g = fast_gelu(v);
                    if (col < H) hbuf[row * H + col] = __float2bfloat16(g);
                    else         gatebf[row * H + (col - H)] = __float2bfloat16(g);
                } else if constexpr (EPI == 1) {
                    const long idx = row * H + col;
                    const float hv = __bfloat162float(hbuf[idx]);
                    hbuf[idx] = __float2bfloat16(hv * v);
                } else {
                    fout[row * D + col] = v;
                }
            }
        }
    }
}

extern "C" void kernel_launch(void* const* d_in, const int* in_sizes, int n_in,
                              void* d_out, int out_size, void* d_ws, size_t ws_size,
                              hipStream_t stream) {
    const float* x      = (const float*)d_in[0];
    const float* ln_w   = (const float*)d_in[1];
    const float* ln_b   = (const float*)d_in[2];
    const float* w_in   = (const float*)d_in[3];
    const float* b_in   = (const float*)d_in[4];
    const float* gln_w  = (const float*)d_in[5];
    const float* gln_b  = (const float*)d_in[6];
    const float* w_gate = (const float*)d_in[7];
    const float* b_gate = (const float*)d_in[8];
    const float* w_out  = (const float*)d_in[9];
    const float* b_out  = (const float*)d_in[10];
    float* out = (float*)d_out;
    (void)d_ws; (void)ws_size;   // scratch lives in g_ws (module global)

    const dim3 tb(32, 8);
    transpose_bf16<<<dim3(N4 / 32, D / 32), tb, 0, stream>>>(w_in,   0, D, N4);
    transpose_bf16<<<dim3(H / 32,  H / 32), tb, 0, stream>>>(w_gate, 1, H, H);
    transpose_bf16<<<dim3(D / 32,  H / 32), tb, 0, stream>>>(w_out,  2, H, D);

    ln1024_kernel<<<M, 256, 0, stream>>>(x, ln_w, ln_b);

    gemm256<0><<<dim3(N4 / 256, M / 256), 512, 0, stream>>>(b_in, nullptr);

    ln2048_stats<<<M, 256, 0, stream>>>();
    cumsum_p1<<<(B * NCH * H) / 256, 256, 0, stream>>>(gln_w, gln_b);
    cumsum_p2<<<(B * H) / 256, 256, 0, stream>>>();
    cumsum_p3<<<(B * NCH * H) / 256, 256, 0, stream>>>(gln_w, gln_b);
    shift_kernel<<<(int)(((size_t)B * S * H) / 256), 256, 0, stream>>>();

    gemm256<1><<<dim3(H / 256, M / 256), 512, 0, stream>>>(b_gate, nullptr);
    gemm256<2><<<dim3(D / 256, M / 256), 512, 0, stream>>>(b_out, out);
}

// Round 8
// 597.795 us; speedup vs baseline: 1.3727x; 1.0041x over previous
//
#include <hip/hip_runtime.h>
#include <hip/hip_bf16.h>
#include <cstdint>

typedef __attribute__((ext_vector_type(8))) short bf16x8;
typedef __attribute__((ext_vector_type(4))) float f32x4;

constexpr int B = 8, S = 2048, D = 1024, H = 2048, N4 = 4096;
constexpr int M = B * S;                 // 16384 rows
constexpr int CHUNK = 128, NCH = S / CHUNK;
constexpr float EPS_LN = 1e-5f, EPS_SHIFT = 1e-5f;

// ---------- all scratch lives in a module-level device global ----------
constexpr size_t SZ_XN     = (size_t)M * D * 2;       // LN(x) bf16
constexpr size_t SZ_HBUF   = (size_t)M * H * 2;       // h half (bf16), gated in place
constexpr size_t SZ_CSUM   = (size_t)M * H * 4;       // fp32 cumsum of LN'd gate
constexpr size_t SZ_SHIFT  = (size_t)M * H * 2;       // shifted gate bf16
constexpr size_t SZ_WT1    = (size_t)N4 * D * 2;      // w_in^T  bf16
constexpr size_t SZ_WT2    = (size_t)H * H * 2;       // w_gate^T bf16
constexpr size_t SZ_WT3    = (size_t)D * H * 2;       // w_out^T bf16
constexpr size_t SZ_PART   = (size_t)B * NCH * H * 4; // cumsum partials
constexpr size_t SZ_GATEBF = (size_t)M * H * 2;       // raw gelu gate bf16 (GEMM1 out)
constexpr size_t SZ_STATS  = (size_t)M * 8;           // per-row (mu, rsig) float2

constexpr size_t OFF_XN     = 0;
constexpr size_t OFF_HBUF   = OFF_XN + SZ_XN;
constexpr size_t OFF_CSUM   = OFF_HBUF + SZ_HBUF;
constexpr size_t OFF_SHIFT  = OFF_CSUM + SZ_CSUM;
constexpr size_t OFF_WT1    = OFF_SHIFT + SZ_SHIFT;
constexpr size_t OFF_WT2    = OFF_WT1 + SZ_WT1;
constexpr size_t OFF_WT3    = OFF_WT2 + SZ_WT2;
constexpr size_t OFF_PART   = OFF_WT3 + SZ_WT3;
constexpr size_t OFF_GATEBF = OFF_PART + SZ_PART;
constexpr size_t OFF_STATS  = OFF_GATEBF + SZ_GATEBF;
constexpr size_t TOTAL_WS   = OFF_STATS + SZ_STATS;   // ~373 MiB

__device__ __attribute__((aligned(1024))) unsigned char g_ws[TOTAL_WS];

__device__ __forceinline__ __hip_bfloat16* ws_xn()     { return (__hip_bfloat16*)(g_ws + OFF_XN); }
__device__ __forceinline__ __hip_bfloat16* ws_hbuf()   { return (__hip_bfloat16*)(g_ws + OFF_HBUF); }
__device__ __forceinline__ float*          ws_csum()   { return (float*)(g_ws + OFF_CSUM); }
__device__ __forceinline__ __hip_bfloat16* ws_shift()  { return (__hip_bfloat16*)(g_ws + OFF_SHIFT); }
__device__ __forceinline__ __hip_bfloat16* ws_wt(int w){
    return (__hip_bfloat16*)(g_ws + (w == 0 ? OFF_WT1 : w == 1 ? OFF_WT2 : OFF_WT3));
}
__device__ __forceinline__ float*          ws_part()   { return (float*)(g_ws + OFF_PART); }
__device__ __forceinline__ __hip_bfloat16* ws_gatebf() { return (__hip_bfloat16*)(g_ws + OFF_GATEBF); }
__device__ __forceinline__ float2*         ws_stats()  { return (float2*)(g_ws + OFF_STATS); }

// async global->LDS DMA, 16 B per lane (dest must be wave-uniform base + lane*16)
__device__ __forceinline__ void gload_lds16(const __hip_bfloat16* gsrc, __hip_bfloat16* ldst) {
    __builtin_amdgcn_global_load_lds(
        (const __attribute__((address_space(1))) void*)gsrc,
        (__attribute__((address_space(3))) void*)ldst, 16, 0, 0);
}

__device__ __forceinline__ void phase_barrier() {
    asm volatile("" ::: "memory");
    __builtin_amdgcn_s_barrier();
    asm volatile("" ::: "memory");
}

__device__ __forceinline__ float bfbits2f(short u) {
    unsigned int x = ((unsigned int)(unsigned short)u) << 16;
    union { unsigned int i; float f; } cv; cv.i = x; return cv.f;
}

// ---- fast exact-GeLU (A&S 7.1.26 minimax erf, |err|<=1.5e-7) ----
__device__ __forceinline__ float fast_gelu(float v) {
    const float x  = v * 0.70710678118654752f;
    const float ax = __builtin_fabsf(x);
    float t;
    asm("v_rcp_f32 %0, %1" : "=v"(t) : "v"(__builtin_fmaf(0.3275911f, ax, 1.0f)));
    float p = __builtin_fmaf(1.061405429f, t, -1.453152027f);
    p = __builtin_fmaf(p, t, 1.421413741f);
    p = __builtin_fmaf(p, t, -0.284496736f);
    p = __builtin_fmaf(p, t, 0.254829592f);
    p *= t;
    float e;   // exp(-x*x)
    asm("v_exp_f32 %0, %1" : "=v"(e) : "v"(ax * ax * -1.4426950408889634f));
    const float erf_abs = __builtin_fmaf(-p, e, 1.0f);
    const float erfv = (x < 0.f) ? -erf_abs : erf_abs;
    return 0.5f * v * (1.0f + erfv);
}

__device__ __forceinline__ void block_reduce2(float& s1, float& s2) {
    #pragma unroll
    for (int off = 32; off > 0; off >>= 1) {
        s1 += __shfl_xor(s1, off);
        s2 += __shfl_xor(s2, off);
    }
    __shared__ float buf[16];
    const int wid = threadIdx.x >> 6;
    const int nw = blockDim.x >> 6;
    if ((threadIdx.x & 63) == 0) { buf[wid] = s1; buf[8 + wid] = s2; }
    __syncthreads();
    if (threadIdx.x < 64) {
        float a = (threadIdx.x < nw) ? buf[threadIdx.x] : 0.f;
        float b = (threadIdx.x < nw) ? buf[8 + threadIdx.x] : 0.f;
        #pragma unroll
        for (int off = 4; off > 0; off >>= 1) { a += __shfl_xor(a, off); b += __shfl_xor(b, off); }
        if (threadIdx.x == 0) { buf[0] = a; buf[8] = b; }
    }
    __syncthreads();
    s1 = buf[0]; s2 = buf[8];
}

// ---- weight transpose + bf16 convert: in[R][C] fp32 -> ws[C][R] bf16 ----
__global__ __launch_bounds__(256) void transpose_bf16(
    const float* __restrict__ in, int which, int R, int C) {
    __hip_bfloat16* __restrict__ out = ws_wt(which);
    __shared__ float tile[32][33];
    const int c0 = blockIdx.x * 32, r0 = blockIdx.y * 32;
    const int tx = threadIdx.x, ty = threadIdx.y;   // block (32,8)
    #pragma unroll
    for (int j = 0; j < 4; ++j)
        tile[ty + j * 8][tx] = in[(size_t)(r0 + ty + j * 8) * C + c0 + tx];
    __syncthreads();
    #pragma unroll
    for (int j = 0; j < 4; ++j)
        out[(size_t)(c0 + ty + j * 8) * R + r0 + tx] = __float2bfloat16(tile[tx][ty + j * 8]);
}

// ---- LN over rows of 1024, fp32 -> bf16 (xn) ----
__global__ __launch_bounds__(256) void ln1024_kernel(
    const float* __restrict__ x, const float* __restrict__ w, const float* __restrict__ b) {
    __hip_bfloat16* __restrict__ out = ws_xn();
    const size_t row = blockIdx.x;
    const float4 v = reinterpret_cast<const float4*>(x + row * D)[threadIdx.x];
    float s = v.x + v.y + v.z + v.w;
    float q = v.x * v.x + v.y * v.y + v.z * v.z + v.w * v.w;
    block_reduce2(s, q);
    const float mu = s * (1.0f / D);
    const float var = q * (1.0f / D) - mu * mu;
    const float rs = rsqrtf(var + EPS_LN);
    const int c = threadIdx.x * 4;
    const float4 wv = reinterpret_cast<const float4*>(w)[threadIdx.x];
    const float4 bv = reinterpret_cast<const float4*>(b)[threadIdx.x];
    __hip_bfloat16* o = out + row * D + c;
    o[0] = __float2bfloat16((v.x - mu) * rs * wv.x + bv.x);
    o[1] = __float2bfloat16((v.y - mu) * rs * wv.y + bv.y);
    o[2] = __float2bfloat16((v.z - mu) * rs * wv.z + bv.z);
    o[3] = __float2bfloat16((v.w - mu) * rs * wv.w + bv.w);
}

// ---- per-row LN stats of gate (bf16 in, float2 (mu, rsig) out) ----
__global__ __launch_bounds__(256) void ln2048_stats() {
    const __hip_bfloat16* __restrict__ g = ws_gatebf();
    const size_t row = blockIdx.x;
    const bf16x8 v = *(const bf16x8*)(g + row * H + threadIdx.x * 8);
    float s = 0.f, q = 0.f;
    #pragma unroll
    for (int j = 0; j < 8; ++j) { const float f = bfbits2f(v[j]); s += f; q += f * f; }
    block_reduce2(s, q);
    if (threadIdx.x == 0) {
        const float mu = s * (1.0f / H);
        const float var = q * (1.0f / H) - mu * mu;
        ws_stats()[row] = make_float2(mu, rsqrtf(var + EPS_LN));
    }
}

// ---- blocked cumsum over LN(gate): p1 chunk sums, p2 prefix, p3 full ----
__global__ __launch_bounds__(256) void cumsum_p1(
    const float* __restrict__ gw, const float* __restrict__ gb) {
    const int idx = blockIdx.x * 256 + threadIdx.x;    // B*NCH*H
    const int c = idx & (H - 1);
    const int ch = (idx >> 11) & (NCH - 1);
    const int b = idx >> 15;
    const int row0 = b * S + ch * CHUNK;
    const __hip_bfloat16* p = ws_gatebf() + (size_t)row0 * H + c;
    const float2* st = ws_stats() + row0;
    const float wv = gw[c], bv = gb[c];
    float s = 0.f;
    #pragma unroll 4
    for (int t = 0; t < CHUNK; ++t) {
        const float g = __bfloat162float(p[(size_t)t * H]);
        const float2 mr = st[t];
        s += (g - mr.x) * mr.y * wv + bv;
    }
    ws_part()[((size_t)b * NCH + ch) * H + c] = s;
}
__global__ __launch_bounds__(256) void cumsum_p2() {
    float* __restrict__ part = ws_part();
    const int idx = blockIdx.x * 256 + threadIdx.x;    // B*H
    const int c = idx & (H - 1);
    const int b = idx >> 11;
    float run = 0.f;
    for (int ch = 0; ch < NCH; ++ch) {
        const size_t o = ((size_t)b * NCH + ch) * H + c;
        const float v = part[o]; part[o] = run; run += v;
    }
}
__global__ __launch_bounds__(256) void cumsum_p3(
    const float* __restrict__ gw, const float* __restrict__ gb) {
    const int idx = blockIdx.x * 256 + threadIdx.x;
    const int c = idx & (H - 1);
    const int ch = (idx >> 11) & (NCH - 1);
    const int b = idx >> 15;
    const int row0 = b * S + ch * CHUNK;
    const __hip_bfloat16* p = ws_gatebf() + (size_t)row0 * H + c;
    const float2* st = ws_stats() + row0;
    float* cs = ws_csum() + (size_t)row0 * H + c;
    const float wv = gw[c], bv = gb[c];
    float run = ws_part()[((size_t)b * NCH + ch) * H + c];
    for (int t = 0; t < CHUNK; ++t) {
        const float g = __bfloat162float(p[(size_t)t * H]);
        const float2 mr = st[t];
        run += (g - mr.x) * mr.y * wv + bv;
        cs[(size_t)t * H] = run;
    }
}

// ---- token shift from cumsum C [B][S][H] -> shifted bf16 [B][S][H] ----
__global__ __launch_bounds__(256) void shift_kernel() {
    const float* __restrict__ Cc = ws_csum();
    __hip_bfloat16* __restrict__ out = ws_shift();
    const size_t idx = (size_t)blockIdx.x * 256 + threadIdx.x;   // B*S*H
    const int c = (int)(idx & (H - 1));
    const int t = (int)((idx >> 11) & (S - 1));
    const int b = (int)(idx >> 22);
    const float* col = Cc + ((size_t)b * S) * H + c;
    const int blk = c >> 8;            // csize = 256
    float val;
    if (blk == 7) {                    // passthrough block: recover gate_n = C[t]-C[t-1]
        const float cur = col[(size_t)t * H];
        const float prev = t ? col[(size_t)(t - 1) * H] : 0.f;
        val = cur - prev;
    } else {
        const int a = 1 << blk;
        const float n1 = (t >= a)     ? col[(size_t)(t - a) * H]     : 0.f;
        const float n2 = (t >= 2 * a) ? col[(size_t)(t - 2 * a) * H] : 0.f;
        const float sd = (float)((t >= a ? t - a : 0) - (t >= 2 * a ? t - 2 * a : 0));
        val = (n1 - n2) / (sd + EPS_SHIFT);
    }
    out[idx] = __float2bfloat16(val);
}

// ============================================================================
// 256x256-tile MFMA GEMM, BK=32, 4 LDS buffers, bank-swizzled, SINGLE-BARRIER
// per K-tile.  Race-safety proof for the 1-barrier schedule:
//  (a) ds_reads of tile t need t's DMA landed+published: counted vmcnt at end
//      of t-1 (drains to 8 = tiles t+2,t+3 still in flight, so t+1's landed)
//      followed by the tile barrier. ✓
//  (b) stage of t+3 into buf[(t-1)&3] needs all waves done reading t-1:
//      t-1's MFMA consumed those ds_reads (compiler lgkmcnt) BEFORE the end-
//      of-(t-1) barrier, and the stage is issued after that barrier. ✓
// No pre-MFMA barrier -> waves run ds_read/MFMA phases skewed (role split,
// T5 prerequisite); MFMA pipe overlaps LDS pipe across waves.
// Bank swizzle verified round 5 (SQ_LDS_BANK_CONFLICT = 0). T1 XCD swizzle.
// EPI 0: A=xn, BT=wT1 (N=4096). v=acc+b_in; gelu; col<H -> hbuf bf16 else gatebf bf16
// EPI 1: A=shifted, BT=wT2 (N=2048). hbuf *= (acc+b_gate)
// EPI 2: A=hbuf, BT=wT3 (N=1024). fout = acc+b_out
// ============================================================================
template<int EPI>
__global__ __launch_bounds__(512, 2) void gemm256(
    const float* __restrict__ bias, float* __restrict__ fout)
{
    constexpr int K = (EPI == 0) ? D : H;
    constexpr int NT = K / 32;
    const __hip_bfloat16* __restrict__ A =
        (EPI == 0) ? ws_xn() : (EPI == 1) ? ws_shift() : ws_hbuf();
    const __hip_bfloat16* __restrict__ BT = ws_wt(EPI);

    __shared__ short smem[4][2][8192];   // [buf][A/B][256 rows x 32 cols] bf16, 128 KiB

    const int tid  = threadIdx.x;
    const int lane = tid & 63;
    const int wid  = tid >> 6;
    const int wr   = wid >> 2;           // 0..1  (M direction, 128 rows each)
    const int wc   = wid & 3;            // 0..3  (N direction, 64 cols each)

    // T1: XCD-aware block swizzle (nwg % 8 == 0 for all three GEMMs).
    const int nbx = gridDim.x;
    const int nwg = nbx * gridDim.y;
    const int bid = blockIdx.y * nbx + blockIdx.x;
    const int swz = (bid & 7) * (nwg >> 3) + (bid >> 3);
    const long bRow = (long)(swz / nbx) * 256;
    const long bCol = (long)(swz % nbx) * 256;

    // staging: thread tid owns LDS chunk tid = (r=tid>>2, c=tid&3); source
    // column is the SWIZZLED chunk sigma_r(c) = c ^ ((r>>1)&3) = c ^ ((tid>>3)&3)
    const int s_r = tid >> 2;            // 0..127
    const int s_c = (((tid & 3) ^ ((tid >> 3) & 3)) << 3);   // pre-swizzled source col
    const __hip_bfloat16* baseA = A  + (bRow + s_r) * (long)K + s_c;
    const __hip_bfloat16* baseB = BT + (bCol + s_r) * (long)K + s_c;
    const long stride128 = 128 * (long)K;

    auto stage_a = [&](int t) {
        short* dst = &smem[t & 3][0][tid * 8];
        gload_lds16(baseA + (long)t * 32,             (__hip_bfloat16*)dst);
        gload_lds16(baseA + (long)t * 32 + stride128, (__hip_bfloat16*)(dst + 4096));
    };
    auto stage_b = [&](int t) {
        short* dst = &smem[t & 3][1][tid * 8];
        gload_lds16(baseB + (long)t * 32,             (__hip_bfloat16*)dst);
        gload_lds16(baseB + (long)t * 32 + stride128, (__hip_bfloat16*)(dst + 4096));
    };

    // fragment read offsets (elements): row*32 + swizzled 16B-chunk * 8.
    const int kk  = (((lane >> 4) ^ ((lane >> 1) & 3)) << 3);
    const int aoff = (wr * 128 + (lane & 15)) * 32 + kk;
    const int boff = (wc * 64  + (lane & 15)) * 32 + kk;

    f32x4 acc[8][4];
    #pragma unroll
    for (int m = 0; m < 8; ++m)
        #pragma unroll
        for (int n = 0; n < 4; ++n)
            acc[m][n] = {0.f, 0.f, 0.f, 0.f};

    // prologue: stage tiles 0,1,2 (12 loads/wave); wait tile0 (8 left in flight)
    stage_a(0); stage_b(0);
    stage_a(1); stage_b(1);
    stage_a(2); stage_b(2);
    asm volatile("s_waitcnt vmcnt(8)" ::: "memory");
    phase_barrier();

    for (int t = 0; t < NT; ++t) {
        const short* bufA = smem[t & 3][0];
        const short* bufB = smem[t & 3][1];
        bf16x8 bf[4], af[8];

        // single phase: all 12 frag reads, both stages of t+3, 32 MFMA,
        // counted drain, ONE barrier.
        #pragma unroll
        for (int n = 0; n < 4; ++n) bf[n] = *(const bf16x8*)&bufB[boff + n * 512];
        #pragma unroll
        for (int m = 0; m < 8; ++m) af[m] = *(const bf16x8*)&bufA[aoff + m * 512];
        if (t + 3 < NT) { stage_a(t + 3); stage_b(t + 3); }
        __builtin_amdgcn_s_setprio(1);
        #pragma unroll
        for (int m = 0; m < 8; ++m)
            #pragma unroll
            for (int n = 0; n < 4; ++n)
                acc[m][n] = __builtin_amdgcn_mfma_f32_16x16x32_bf16(af[m], bf[n], acc[m][n], 0, 0, 0);
        __builtin_amdgcn_s_setprio(0);
        if (t + 1 < NT) {   // ensure tile t+1 landed before its ds_reads (next iter)
            const int fly = ((NT - 1 < t + 3) ? NT - 1 : t + 3) - (t + 1);
            if (fly >= 2)      asm volatile("s_waitcnt vmcnt(8)" ::: "memory");
            else if (fly == 1) asm volatile("s_waitcnt vmcnt(4)" ::: "memory");
            else               asm volatile("s_waitcnt vmcnt(0)" ::: "memory");
        }
        phase_barrier();
    }

    // ---- epilogue ----
    __hip_bfloat16* __restrict__ hbuf = ws_hbuf();
    __hip_bfloat16* __restrict__ gatebf = ws_gatebf();
    const int lr = lane & 15;
    const int lrow4 = (lane >> 4) << 2;   // C/D: col=lane&15, row=(lane>>4)*4+r
    #pragma unroll
    for (int m = 0; m < 8; ++m) {
        #pragma unroll
        for (int n = 0; n < 4; ++n) {
            const long col = bCol + wc * 64 + n * 16 + lr;
            const float bv = bias[col];
            #pragma unroll
            for (int r = 0; r < 4; ++r) {
                const long row = bRow + wr * 128 + m * 16 + lrow4 + r;
                float v = acc[m][n][r] + bv;
                if constexpr (EPI == 0) {
                    const float g = fast_gelu(v);
                    if (col < H) hbuf[row * H + col] = __float2bfloat16(g);
                    else         gatebf[row * H + (col - H)] = __float2bfloat16(g);
                } else if constexpr (EPI == 1) {
                    const long idx = row * H + col;
                    const float hv = __bfloat162float(hbuf[idx]);
                    hbuf[idx] = __float2bfloat16(hv * v);
                } else {
                    fout[row * D + col] = v;
                }
            }
        }
    }
}

extern "C" void kernel_launch(void* const* d_in, const int* in_sizes, int n_in,
                              void* d_out, int out_size, void* d_ws, size_t ws_size,
                              hipStream_t stream) {
    const float* x      = (const float*)d_in[0];
    const float* ln_w   = (const float*)d_in[1];
    const float* ln_b   = (const float*)d_in[2];
    const float* w_in   = (const float*)d_in[3];
    const float* b_in   = (const float*)d_in[4];
    const float* gln_w  = (const float*)d_in[5];
    const float* gln_b  = (const float*)d_in[6];
    const float* w_gate = (const float*)d_in[7];
    const float* b_gate = (const float*)d_in[8];
    const float* w_out  = (const float*)d_in[9];
    const float* b_out  = (const float*)d_in[10];
    float* out = (float*)d_out;
    (void)d_ws; (void)ws_size;   // scratch lives in g_ws (module global)

    const dim3 tb(32, 8);
    transpose_bf16<<<dim3(N4 / 32, D / 32), tb, 0, stream>>>(w_in,   0, D, N4);
    transpose_bf16<<<dim3(H / 32,  H / 32), tb, 0, stream>>>(w_gate, 1, H, H);
    transpose_bf16<<<dim3(D / 32,  H / 32), tb, 0, stream>>>(w_out,  2, H, D);

    ln1024_kernel<<<M, 256, 0, stream>>>(x, ln_w, ln_b);

    gemm256<0><<<dim3(N4 / 256, M / 256), 512, 0, stream>>>(b_in, nullptr);

    ln2048_stats<<<M, 256, 0, stream>>>();
    cumsum_p1<<<(B * NCH * H) / 256, 256, 0, stream>>>(gln_w, gln_b);
    cumsum_p2<<<(B * H) / 256, 256, 0, stream>>>();
    cumsum_p3<<<(B * NCH * H) / 256, 256, 0, stream>>>(gln_w, gln_b);
    shift_kernel<<<(int)(((size_t)B * S * H) / 256), 256, 0, stream>>>();

    gemm256<1><<<dim3(H / 256, M / 256), 512, 0, stream>>>(b_gate, nullptr);
    gemm256<2><<<dim3(D / 256, M / 256), 512, 0, stream>>>(b_out, out);
}

// Round 9
// 570.168 us; speedup vs baseline: 1.4392x; 1.0485x over previous
//
#include <hip/hip_runtime.h>
#include <hip/hip_bf16.h>
#include <cstdint>

typedef __attribute__((ext_vector_type(8))) short bf16x8;
typedef __attribute__((ext_vector_type(4))) float f32x4;

constexpr int B = 8, S = 2048, D = 1024, H = 2048, N4 = 4096;
constexpr int M = B * S;                 // 16384 rows
constexpr int CHUNK = 128, NCH = S / CHUNK;
constexpr float EPS_LN = 1e-5f, EPS_SHIFT = 1e-5f;

// ---------- all scratch lives in a module-level device global ----------
constexpr size_t SZ_XN     = (size_t)M * D * 2;       // LN(x) bf16
constexpr size_t SZ_HBUF   = (size_t)M * H * 2;       // h half (bf16), gated in place
constexpr size_t SZ_SHIFT  = (size_t)M * H * 2;       // shifted gate bf16
constexpr size_t SZ_WT1    = (size_t)N4 * D * 2;      // w_in^T  bf16
constexpr size_t SZ_WT2    = (size_t)H * H * 2;       // w_gate^T bf16
constexpr size_t SZ_WT3    = (size_t)D * H * 2;       // w_out^T bf16
constexpr size_t SZ_PART   = (size_t)B * NCH * H * 4; // cumsum partials
constexpr size_t SZ_GATEBF = (size_t)M * H * 2;       // raw gelu gate bf16 (GEMM1 out)
constexpr size_t SZ_STATS  = (size_t)M * 8;           // per-row (mu, rsig) float2

constexpr size_t OFF_XN     = 0;
constexpr size_t OFF_HBUF   = OFF_XN + SZ_XN;
constexpr size_t OFF_SHIFT  = OFF_HBUF + SZ_HBUF;
constexpr size_t OFF_WT1    = OFF_SHIFT + SZ_SHIFT;
constexpr size_t OFF_WT2    = OFF_WT1 + SZ_WT1;
constexpr size_t OFF_WT3    = OFF_WT2 + SZ_WT2;
constexpr size_t OFF_PART   = OFF_WT3 + SZ_WT3;
constexpr size_t OFF_GATEBF = OFF_PART + SZ_PART;
constexpr size_t OFF_STATS  = OFF_GATEBF + SZ_GATEBF;
constexpr size_t TOTAL_WS   = OFF_STATS + SZ_STATS;   // ~245 MiB (csum removed)

__device__ __attribute__((aligned(1024))) unsigned char g_ws[TOTAL_WS];

__device__ __forceinline__ __hip_bfloat16* ws_xn()     { return (__hip_bfloat16*)(g_ws + OFF_XN); }
__device__ __forceinline__ __hip_bfloat16* ws_hbuf()   { return (__hip_bfloat16*)(g_ws + OFF_HBUF); }
__device__ __forceinline__ __hip_bfloat16* ws_shift()  { return (__hip_bfloat16*)(g_ws + OFF_SHIFT); }
__device__ __forceinline__ __hip_bfloat16* ws_wt(int w){
    return (__hip_bfloat16*)(g_ws + (w == 0 ? OFF_WT1 : w == 1 ? OFF_WT2 : OFF_WT3));
}
__device__ __forceinline__ float*          ws_part()   { return (float*)(g_ws + OFF_PART); }
__device__ __forceinline__ __hip_bfloat16* ws_gatebf() { return (__hip_bfloat16*)(g_ws + OFF_GATEBF); }
__device__ __forceinline__ float2*         ws_stats()  { return (float2*)(g_ws + OFF_STATS); }

// async global->LDS DMA, 16 B per lane (dest must be wave-uniform base + lane*16)
__device__ __forceinline__ void gload_lds16(const __hip_bfloat16* gsrc, __hip_bfloat16* ldst) {
    __builtin_amdgcn_global_load_lds(
        (const __attribute__((address_space(1))) void*)gsrc,
        (__attribute__((address_space(3))) void*)ldst, 16, 0, 0);
}

__device__ __forceinline__ void phase_barrier() {
    asm volatile("" ::: "memory");
    __builtin_amdgcn_s_barrier();
    asm volatile("" ::: "memory");
}

__device__ __forceinline__ float bfbits2f(short u) {
    unsigned int x = ((unsigned int)(unsigned short)u) << 16;
    union { unsigned int i; float f; } cv; cv.i = x; return cv.f;
}

// ---- fast exact-GeLU (A&S 7.1.26 minimax erf, |err|<=1.5e-7) ----
__device__ __forceinline__ float fast_gelu(float v) {
    const float x  = v * 0.70710678118654752f;
    const float ax = __builtin_fabsf(x);
    float t;
    asm("v_rcp_f32 %0, %1" : "=v"(t) : "v"(__builtin_fmaf(0.3275911f, ax, 1.0f)));
    float p = __builtin_fmaf(1.061405429f, t, -1.453152027f);
    p = __builtin_fmaf(p, t, 1.421413741f);
    p = __builtin_fmaf(p, t, -0.284496736f);
    p = __builtin_fmaf(p, t, 0.254829592f);
    p *= t;
    float e;   // exp(-x*x)
    asm("v_exp_f32 %0, %1" : "=v"(e) : "v"(ax * ax * -1.4426950408889634f));
    const float erf_abs = __builtin_fmaf(-p, e, 1.0f);
    const float erfv = (x < 0.f) ? -erf_abs : erf_abs;
    return 0.5f * v * (1.0f + erfv);
}

__device__ __forceinline__ void block_reduce2(float& s1, float& s2) {
    #pragma unroll
    for (int off = 32; off > 0; off >>= 1) {
        s1 += __shfl_xor(s1, off);
        s2 += __shfl_xor(s2, off);
    }
    __shared__ float buf[16];
    const int wid = threadIdx.x >> 6;
    const int nw = blockDim.x >> 6;
    if ((threadIdx.x & 63) == 0) { buf[wid] = s1; buf[8 + wid] = s2; }
    __syncthreads();
    if (threadIdx.x < 64) {
        float a = (threadIdx.x < nw) ? buf[threadIdx.x] : 0.f;
        float b = (threadIdx.x < nw) ? buf[8 + threadIdx.x] : 0.f;
        #pragma unroll
        for (int off = 4; off > 0; off >>= 1) { a += __shfl_xor(a, off); b += __shfl_xor(b, off); }
        if (threadIdx.x == 0) { buf[0] = a; buf[8] = b; }
    }
    __syncthreads();
    s1 = buf[0]; s2 = buf[8];
}

// ---- weight transpose + bf16 convert: in[R][C] fp32 -> ws[C][R] bf16 ----
__global__ __launch_bounds__(256) void transpose_bf16(
    const float* __restrict__ in, int which, int R, int C) {
    __hip_bfloat16* __restrict__ out = ws_wt(which);
    __shared__ float tile[32][33];
    const int c0 = blockIdx.x * 32, r0 = blockIdx.y * 32;
    const int tx = threadIdx.x, ty = threadIdx.y;   // block (32,8)
    #pragma unroll
    for (int j = 0; j < 4; ++j)
        tile[ty + j * 8][tx] = in[(size_t)(r0 + ty + j * 8) * C + c0 + tx];
    __syncthreads();
    #pragma unroll
    for (int j = 0; j < 4; ++j)
        out[(size_t)(c0 + ty + j * 8) * R + r0 + tx] = __float2bfloat16(tile[tx][ty + j * 8]);
}

// ---- LN over rows of 1024, fp32 -> bf16 (xn) ----
__global__ __launch_bounds__(256) void ln1024_kernel(
    const float* __restrict__ x, const float* __restrict__ w, const float* __restrict__ b) {
    __hip_bfloat16* __restrict__ out = ws_xn();
    const size_t row = blockIdx.x;
    const float4 v = reinterpret_cast<const float4*>(x + row * D)[threadIdx.x];
    float s = v.x + v.y + v.z + v.w;
    float q = v.x * v.x + v.y * v.y + v.z * v.z + v.w * v.w;
    block_reduce2(s, q);
    const float mu = s * (1.0f / D);
    const float var = q * (1.0f / D) - mu * mu;
    const float rs = rsqrtf(var + EPS_LN);
    const int c = threadIdx.x * 4;
    const float4 wv = reinterpret_cast<const float4*>(w)[threadIdx.x];
    const float4 bv = reinterpret_cast<const float4*>(b)[threadIdx.x];
    __hip_bfloat16* o = out + row * D + c;
    o[0] = __float2bfloat16((v.x - mu) * rs * wv.x + bv.x);
    o[1] = __float2bfloat16((v.y - mu) * rs * wv.y + bv.y);
    o[2] = __float2bfloat16((v.z - mu) * rs * wv.z + bv.z);
    o[3] = __float2bfloat16((v.w - mu) * rs * wv.w + bv.w);
}

// ---- per-row LN stats of gate (bf16 in, float2 (mu, rsig) out) ----
__global__ __launch_bounds__(256) void ln2048_stats() {
    const __hip_bfloat16* __restrict__ g = ws_gatebf();
    const size_t row = blockIdx.x;
    const bf16x8 v = *(const bf16x8*)(g + row * H + threadIdx.x * 8);
    float s = 0.f, q = 0.f;
    #pragma unroll
    for (int j = 0; j < 8; ++j) { const float f = bfbits2f(v[j]); s += f; q += f * f; }
    block_reduce2(s, q);
    if (threadIdx.x == 0) {
        const float mu = s * (1.0f / H);
        const float var = q * (1.0f / H) - mu * mu;
        ws_stats()[row] = make_float2(mu, rsqrtf(var + EPS_LN));
    }
}

// ---- blocked cumsum over LN(gate): p1 chunk sums, p2 exclusive prefix ----
__global__ __launch_bounds__(256) void cumsum_p1(
    const float* __restrict__ gw, const float* __restrict__ gb) {
    const int idx = blockIdx.x * 256 + threadIdx.x;    // B*NCH*H
    const int c = idx & (H - 1);
    const int ch = (idx >> 11) & (NCH - 1);
    const int b = idx >> 15;
    const int row0 = b * S + ch * CHUNK;
    const __hip_bfloat16* p = ws_gatebf() + (size_t)row0 * H + c;
    const float2* st = ws_stats() + row0;
    const float wv = gw[c], bv = gb[c];
    float s = 0.f;
    #pragma unroll 4
    for (int t = 0; t < CHUNK; ++t) {
        const float g = __bfloat162float(p[(size_t)t * H]);
        const float2 mr = st[t];
        s += (g - mr.x) * mr.y * wv + bv;
    }
    ws_part()[((size_t)b * NCH + ch) * H + c] = s;
}
__global__ __launch_bounds__(256) void cumsum_p2() {
    float* __restrict__ part = ws_part();
    const int idx = blockIdx.x * 256 + threadIdx.x;    // B*H
    const int c = idx & (H - 1);
    const int b = idx >> 11;
    float run = 0.f;
    for (int ch = 0; ch < NCH; ++ch) {
        const size_t o = ((size_t)b * NCH + ch) * H + c;
        const float v = part[o]; part[o] = run; run += v;
    }
}

// ============================================================================
// FUSED cumsum_p3 + shift: walks each 128-token chunk computing the running
// cumsum of LN(gate) in fp32 and emits shifted bf16 DIRECTLY, keeping the
// last 2a C-values in a compile-time register ring (static unroll, rule #20).
// Boundary lags (up to t-128) are served by a prewalk of the previous chunk
// (ring slot algebra: after prewalk, slot (u-A)&(2A-1) == C[t-A] for u<A).
// Kills the 128 MB fp32 csum buffer + the separate 192 MB shift pass.
// BLK 7 = passthrough channels: shifted = LN'd gate value directly.
// ============================================================================
template<int BLK>
__device__ __forceinline__ void cumshift_body(
    const float* __restrict__ gw, const float* __restrict__ gb) {
    const int bidx = blockIdx.x;          // grid.x = B*NCH
    const int ch = bidx & (NCH - 1);
    const int b  = bidx >> 4;             // NCH = 16
    const int c  = BLK * 256 + threadIdx.x;
    const int row0 = b * S + ch * CHUNK;
    const __hip_bfloat16* __restrict__ gp = ws_gatebf() + (size_t)row0 * H + c;
    const float2* __restrict__ st = ws_stats() + row0;
    __hip_bfloat16* __restrict__ outp = ws_shift() + (size_t)row0 * H + c;
    const float wv = gw[c], bv = gb[c];

    if constexpr (BLK == 7) {
        #pragma unroll 8
        for (int u = 0; u < CHUNK; ++u) {
            const float g = __bfloat162float(gp[(size_t)u * H]);
            const float2 mr = st[u];
            outp[(size_t)u * H] = __float2bfloat16((g - mr.x) * mr.y * wv + bv);
        }
    } else {
        constexpr int A  = 1 << BLK;
        constexpr int RM = 2 * A - 1;     // ring mask (2A divides 128)
        float ring[2 * A];
        float run;
        if (ch > 0) {
            run = ws_part()[((size_t)b * NCH + ch - 1) * H + c];
            const __hip_bfloat16* pp = gp - (size_t)CHUNK * H;
            const float2* stp = st - CHUNK;
            #pragma unroll
            for (int u = 0; u < CHUNK; ++u) {
                const float g = __bfloat162float(pp[(size_t)u * H]);
                const float2 mr = stp[u];
                run += (g - mr.x) * mr.y * wv + bv;
                ring[u & RM] = run;
            }
        } else {
            run = 0.f;
            #pragma unroll
            for (int i = 0; i < 2 * A; ++i) ring[i] = 0.f;
        }
        const int t0 = ch * CHUNK;
        #pragma unroll
        for (int u = 0; u < CHUNK; ++u) {
            const int t = t0 + u;
            const float g = __bfloat162float(gp[(size_t)u * H]);
            const float2 mr = st[u];
            run += (g - mr.x) * mr.y * wv + bv;
            // read lags BEFORE overwriting slot u&RM (slot u&RM still holds C[t-2A])
            const float n1 = (t >= A)     ? ring[(u - A) & RM]     : 0.f;
            const float n2 = (t >= 2 * A) ? ring[(u - 2 * A) & RM] : 0.f;
            const float sd = (float)((t >= A ? t - A : 0) - (t >= 2 * A ? t - 2 * A : 0));
            outp[(size_t)u * H] = __float2bfloat16((n1 - n2) / (sd + EPS_SHIFT));
            ring[u & RM] = run;
        }
    }
}

__global__ __launch_bounds__(256) void cumsum_shift(
    const float* __restrict__ gw, const float* __restrict__ gb) {
    switch (blockIdx.y) {                 // grid.y = 8 channel blocks (uniform per block)
        case 0: cumshift_body<0>(gw, gb); break;
        case 1: cumshift_body<1>(gw, gb); break;
        case 2: cumshift_body<2>(gw, gb); break;
        case 3: cumshift_body<3>(gw, gb); break;
        case 4: cumshift_body<4>(gw, gb); break;
        case 5: cumshift_body<5>(gw, gb); break;
        case 6: cumshift_body<6>(gw, gb); break;
        default: cumshift_body<7>(gw, gb); break;
    }
}

// ============================================================================
// 256x256-tile MFMA GEMM, BK=32, 4 LDS buffers, bank-swizzled, SINGLE-BARRIER
// per K-tile (race proof in r7/r8 notes; SQ_LDS_BANK_CONFLICT = 0 measured).
// T1 XCD swizzle on the grid.
// EPI 0: A=xn, BT=wT1 (N=4096). v=acc+b_in; gelu; col<H -> hbuf bf16 else gatebf bf16
// EPI 1: A=shifted, BT=wT2 (N=2048). hbuf *= (acc+b_gate)
// EPI 2: A=hbuf, BT=wT3 (N=1024). fout = acc+b_out
// ============================================================================
template<int EPI>
__global__ __launch_bounds__(512, 2) void gemm256(
    const float* __restrict__ bias, float* __restrict__ fout)
{
    constexpr int K = (EPI == 0) ? D : H;
    constexpr int NT = K / 32;
    const __hip_bfloat16* __restrict__ A =
        (EPI == 0) ? ws_xn() : (EPI == 1) ? ws_shift() : ws_hbuf();
    const __hip_bfloat16* __restrict__ BT = ws_wt(EPI);

    __shared__ short smem[4][2][8192];   // [buf][A/B][256 rows x 32 cols] bf16, 128 KiB

    const int tid  = threadIdx.x;
    const int lane = tid & 63;
    const int wid  = tid >> 6;
    const int wr   = wid >> 2;           // 0..1  (M direction, 128 rows each)
    const int wc   = wid & 3;            // 0..3  (N direction, 64 cols each)

    // T1: XCD-aware block swizzle (nwg % 8 == 0 for all three GEMMs).
    const int nbx = gridDim.x;
    const int nwg = nbx * gridDim.y;
    const int bid = blockIdx.y * nbx + blockIdx.x;
    const int swz = (bid & 7) * (nwg >> 3) + (bid >> 3);
    const long bRow = (long)(swz / nbx) * 256;
    const long bCol = (long)(swz % nbx) * 256;

    // staging: thread tid owns LDS chunk tid = (r=tid>>2, c=tid&3); source
    // column is the SWIZZLED chunk sigma_r(c) = c ^ ((r>>1)&3) = c ^ ((tid>>3)&3)
    const int s_r = tid >> 2;            // 0..127
    const int s_c = (((tid & 3) ^ ((tid >> 3) & 3)) << 3);   // pre-swizzled source col
    const __hip_bfloat16* baseA = A  + (bRow + s_r) * (long)K + s_c;
    const __hip_bfloat16* baseB = BT + (bCol + s_r) * (long)K + s_c;
    const long stride128 = 128 * (long)K;

    auto stage_a = [&](int t) {
        short* dst = &smem[t & 3][0][tid * 8];
        gload_lds16(baseA + (long)t * 32,             (__hip_bfloat16*)dst);
        gload_lds16(baseA + (long)t * 32 + stride128, (__hip_bfloat16*)(dst + 4096));
    };
    auto stage_b = [&](int t) {
        short* dst = &smem[t & 3][1][tid * 8];
        gload_lds16(baseB + (long)t * 32,             (__hip_bfloat16*)dst);
        gload_lds16(baseB + (long)t * 32 + stride128, (__hip_bfloat16*)(dst + 4096));
    };

    // fragment read offsets (elements): row*32 + swizzled 16B-chunk * 8.
    const int kk  = (((lane >> 4) ^ ((lane >> 1) & 3)) << 3);
    const int aoff = (wr * 128 + (lane & 15)) * 32 + kk;
    const int boff = (wc * 64  + (lane & 15)) * 32 + kk;

    f32x4 acc[8][4];
    #pragma unroll
    for (int m = 0; m < 8; ++m)
        #pragma unroll
        for (int n = 0; n < 4; ++n)
            acc[m][n] = {0.f, 0.f, 0.f, 0.f};

    // prologue: stage tiles 0,1,2 (12 loads/wave); wait tile0 (8 left in flight)
    stage_a(0); stage_b(0);
    stage_a(1); stage_b(1);
    stage_a(2); stage_b(2);
    asm volatile("s_waitcnt vmcnt(8)" ::: "memory");
    phase_barrier();

    for (int t = 0; t < NT; ++t) {
        const short* bufA = smem[t & 3][0];
        const short* bufB = smem[t & 3][1];
        bf16x8 bf[4], af[8];

        #pragma unroll
        for (int n = 0; n < 4; ++n) bf[n] = *(const bf16x8*)&bufB[boff + n * 512];
        #pragma unroll
        for (int m = 0; m < 8; ++m) af[m] = *(const bf16x8*)&bufA[aoff + m * 512];
        if (t + 3 < NT) { stage_a(t + 3); stage_b(t + 3); }
        __builtin_amdgcn_s_setprio(1);
        #pragma unroll
        for (int m = 0; m < 8; ++m)
            #pragma unroll
            for (int n = 0; n < 4; ++n)
                acc[m][n] = __builtin_amdgcn_mfma_f32_16x16x32_bf16(af[m], bf[n], acc[m][n], 0, 0, 0);
        __builtin_amdgcn_s_setprio(0);
        if (t + 1 < NT) {   // ensure tile t+1 landed before its ds_reads (next iter)
            const int fly = ((NT - 1 < t + 3) ? NT - 1 : t + 3) - (t + 1);
            if (fly >= 2)      asm volatile("s_waitcnt vmcnt(8)" ::: "memory");
            else if (fly == 1) asm volatile("s_waitcnt vmcnt(4)" ::: "memory");
            else               asm volatile("s_waitcnt vmcnt(0)" ::: "memory");
        }
        phase_barrier();
    }

    // ---- epilogue ----
    __hip_bfloat16* __restrict__ hbuf = ws_hbuf();
    __hip_bfloat16* __restrict__ gatebf = ws_gatebf();
    const int lr = lane & 15;
    const int lrow4 = (lane >> 4) << 2;   // C/D: col=lane&15, row=(lane>>4)*4+r
    #pragma unroll
    for (int m = 0; m < 8; ++m) {
        #pragma unroll
        for (int n = 0; n < 4; ++n) {
            const long col = bCol + wc * 64 + n * 16 + lr;
            const float bv = bias[col];
            #pragma unroll
            for (int r = 0; r < 4; ++r) {
                const long row = bRow + wr * 128 + m * 16 + lrow4 + r;
                float v = acc[m][n][r] + bv;
                if constexpr (EPI == 0) {
                    const float g = fast_gelu(v);
                    if (col < H) hbuf[row * H + col] = __float2bfloat16(g);
                    else         gatebf[row * H + (col - H)] = __float2bfloat16(g);
                } else if constexpr (EPI == 1) {
                    const long idx = row * H + col;
                    const float hv = __bfloat162float(hbuf[idx]);
                    hbuf[idx] = __float2bfloat16(hv * v);
                } else {
                    fout[row * D + col] = v;
                }
            }
        }
    }
}

extern "C" void kernel_launch(void* const* d_in, const int* in_sizes, int n_in,
                              void* d_out, int out_size, void* d_ws, size_t ws_size,
                              hipStream_t stream) {
    const float* x      = (const float*)d_in[0];
    const float* ln_w   = (const float*)d_in[1];
    const float* ln_b   = (const float*)d_in[2];
    const float* w_in   = (const float*)d_in[3];
    const float* b_in   = (const float*)d_in[4];
    const float* gln_w  = (const float*)d_in[5];
    const float* gln_b  = (const float*)d_in[6];
    const float* w_gate = (const float*)d_in[7];
    const float* b_gate = (const float*)d_in[8];
    const float* w_out  = (const float*)d_in[9];
    const float* b_out  = (const float*)d_in[10];
    float* out = (float*)d_out;
    (void)d_ws; (void)ws_size;   // scratch lives in g_ws (module global)

    const dim3 tb(32, 8);
    transpose_bf16<<<dim3(N4 / 32, D / 32), tb, 0, stream>>>(w_in,   0, D, N4);
    transpose_bf16<<<dim3(H / 32,  H / 32), tb, 0, stream>>>(w_gate, 1, H, H);
    transpose_bf16<<<dim3(D / 32,  H / 32), tb, 0, stream>>>(w_out,  2, H, D);

    ln1024_kernel<<<M, 256, 0, stream>>>(x, ln_w, ln_b);

    gemm256<0><<<dim3(N4 / 256, M / 256), 512, 0, stream>>>(b_in, nullptr);

    ln2048_stats<<<M, 256, 0, stream>>>();
    cumsum_p1<<<(B * NCH * H) / 256, 256, 0, stream>>>(gln_w, gln_b);
    cumsum_p2<<<(B * H) / 256, 256, 0, stream>>>();
    cumsum_shift<<<dim3(B * NCH, 8), 256, 0, stream>>>(gln_w, gln_b);

    gemm256<1><<<dim3(H / 256, M / 256), 512, 0, stream>>>(b_gate, nullptr);
    gemm256<2><<<dim3(D / 256, M / 256), 512, 0, stream>>>(b_out, out);
}